// Round 1
// baseline (2195.190 us; speedup 1.0000x reference)
//
#include <hip/hip_runtime.h>
#include <math.h>

typedef unsigned int u32;
typedef unsigned short u16;

#define NTOK 98
#define NWIN 1024
#define QS 40            // padded qkv row stride in u16 (80B -> even bank spread for b128)
#define MS (98*QS)       // per-matrix section in qkvs

__device__ __forceinline__ float bflo(u32 u){ union{u32 i; float f;} c; c.i = u<<16; return c.f; }
__device__ __forceinline__ float bfhi(u32 u){ union{u32 i; float f;} c; c.i = u & 0xffff0000u; return c.f; }
__device__ __forceinline__ u16 f2bf(float f){
  union{float f; u32 i;} c; c.f = f;
  u32 x = c.i;
  return (u16)((x + 0x7fffu + ((x>>16)&1u)) >> 16);
}

// token (win,t) maps to source coords (read of shifted xn) AND destination of
// window_reverse+unroll (the rolls cancel): d=(db*2+di+1)%16, h=(hb*7+hi+3)%56, w=(wb*7+wi+3)%56
__device__ __forceinline__ int src_token(int win, int t){
  int b  = win >> 9;
  int wr = win & 511;
  int db = wr >> 6, hb = (wr >> 3) & 7, wb = wr & 7;
  int di = t / 49, r = t - di*49;
  int hi = r / 7,  wi = r - hi*7;
  int d = (db*2 + di + 1) & 15;
  int h = hb*7 + hi + 3; if (h >= 56) h -= 56;
  int w = wb*7 + wi + 3; if (w >= 56) w -= 56;
  return ((b*16 + d)*56 + h)*56 + w;
}

// ---------------- K1: LN(x2) + shift + window partition -> xn (bf16) ----------------
__global__ __launch_bounds__(256) void k1_ln(const float* __restrict__ x,
      const float* __restrict__ g, const float* __restrict__ bb, u16* __restrict__ xn){
  int wid  = (blockIdx.x << 2) + (threadIdx.x >> 6);
  int lane = threadIdx.x & 63;
  if (wid >= NWIN*NTOK) return;
  int win = wid / NTOK, t = wid - win*NTOK;
  int tok = src_token(win, t);
  const float* xp = x + (size_t)tok*192 + 96;
  float a0 = 0.f, a1 = 0.f;
  if (lane < 48){ float2 v = *(const float2*)(xp + (lane<<1)); a0 = v.x; a1 = v.y; }
  float s = a0 + a1, s2 = a0*a0 + a1*a1;
  #pragma unroll
  for (int o = 32; o; o >>= 1){ s += __shfl_xor(s, o); s2 += __shfl_xor(s2, o); }
  float mean = s * (1.f/96.f);
  float rstd = rsqrtf(s2*(1.f/96.f) - mean*mean + 1e-5f);
  if (lane < 48){
    float r0 = (a0-mean)*rstd*g[2*lane]   + bb[2*lane];
    float r1 = (a1-mean)*rstd*g[2*lane+1] + bb[2*lane+1];
    u32 pk = (u32)f2bf(r0) | ((u32)f2bf(r1) << 16);
    *(u32*)(xn + (size_t)wid*96 + (lane<<1)) = pk;
  }
}

// ---------------- K2: per (window, head) attention ----------------
__global__ __launch_bounds__(256) void k2_attn(const u16* __restrict__ xn,
    const float* __restrict__ qkv_w, const float* __restrict__ qkv_b,
    const float* __restrict__ bias_tab, const int* __restrict__ rel_idx,
    const float* __restrict__ mask, u16* __restrict__ attn_o){
  __shared__ __align__(16) float sm[98*99];      // S (stride 99); first 9408 floats alias xn-f32
  __shared__ __align__(16) u16 qkvs[3*MS];       // q,k,v rows padded to QS
  __shared__ float rowinv[98];
  int tid = threadIdx.x;
  int win = blockIdx.x / 3;
  int hd  = blockIdx.x - win*3;

  // A: load xn (bf16) -> f32 LDS
  const u32* xw = (const u32*)(xn + (size_t)win*98*96);
  for (int i = tid; i < 98*48; i += 256){
    u32 u = xw[i];
    sm[2*i] = bflo(u); sm[2*i+1] = bfhi(u);
  }
  __syncthreads();

  // B: q,k,v for this head (scale folded into q)
  for (int u = tid; u < 3*98*32; u += 256){
    int m = u / 3136; int r = u - m*3136;
    int t = r >> 5, c = r & 31;
    int row = m*96 + hd*32 + c;
    float acc = qkv_b[row];
    const float4* wp = (const float4*)(qkv_w + row*96);
    const float4* ap = (const float4*)(sm + t*96);
    #pragma unroll 6
    for (int k = 0; k < 24; k++){
      float4 w4 = wp[k], a4 = ap[k];
      acc += w4.x*a4.x + w4.y*a4.y + w4.z*a4.z + w4.w*a4.w;
    }
    if (m == 0) acc *= 0.17677669529663687f;
    qkvs[m*MS + t*QS + c] = f2bf(acc);
  }
  __syncthreads();

  // C: S = q k^T + bias + mask  (overwrites xn alias region)
  const float* mrow = mask + (size_t)(win & 511)*9604;
  for (int u = tid; u < 9604; u += 256){
    int i = u / 98, j = u - i*98;
    const uint4* qp = (const uint4*)(qkvs + i*QS);
    const uint4* kp = (const uint4*)(qkvs + MS + j*QS);
    float acc = 0.f;
    #pragma unroll
    for (int m = 0; m < 4; m++){
      uint4 q4 = qp[m], k4 = kp[m];
      acc += bflo(q4.x)*bflo(k4.x) + bfhi(q4.x)*bfhi(k4.x);
      acc += bflo(q4.y)*bflo(k4.y) + bfhi(q4.y)*bfhi(k4.y);
      acc += bflo(q4.z)*bflo(k4.z) + bfhi(q4.z)*bfhi(k4.z);
      acc += bflo(q4.w)*bflo(k4.w) + bfhi(q4.w)*bfhi(k4.w);
    }
    acc += bias_tab[rel_idx[u]*3 + hd] + mrow[u];
    sm[i*99 + j] = acc;
  }
  __syncthreads();

  // D: per-row softmax stats (exp in place, 1/sum deferred to PV)
  if (tid < 98){
    float* Sr = sm + tid*99;
    float mx = -1e30f;
    for (int j = 0; j < 98; j++) mx = fmaxf(mx, Sr[j]);
    float sum = 0.f;
    for (int j = 0; j < 98; j++){ float e = __expf(Sr[j] - mx); Sr[j] = e; sum += e; }
    rowinv[tid] = 1.f / sum;
  }
  __syncthreads();

  // E: O = (P V) * rowinv -> attn_o bf16
  for (int u = tid; u < 98*16; u += 256){
    int i = u >> 4, cp = u & 15;
    const float* Pr = sm + i*99;
    const u32* vp = (const u32*)(qkvs + 2*MS) + cp;   // row stride QS/2=20 u32
    float acc0 = 0.f, acc1 = 0.f;
    for (int j = 0; j < 98; j++){
      float p = Pr[j];
      u32 vv = vp[j*20];
      acc0 += p * bflo(vv);
      acc1 += p * bfhi(vv);
    }
    float inv = rowinv[i];
    u32 pk = (u32)f2bf(acc0*inv) | ((u32)f2bf(acc1*inv) << 16);
    *(u32*)(attn_o + ((size_t)win*98 + i)*96 + hd*32 + 2*cp) = pk;
  }
}

// ---------------- K3: proj + x1 add -> y1 (out[...,0:96]) ----------------
__global__ __launch_bounds__(256) void k3_proj(const u16* __restrict__ attn_o,
    const float* __restrict__ pw, const float* __restrict__ pb,
    const float* __restrict__ x, float* __restrict__ out){
  __shared__ __align__(16) float aw[16*96];
  int tid = threadIdx.x;
  int base = blockIdx.x * 16;
  const u32* src = (const u32*)(attn_o + (size_t)base*96);
  for (int i = tid; i < 16*48; i += 256){
    u32 u = src[i]; aw[2*i] = bflo(u); aw[2*i+1] = bfhi(u);
  }
  __syncthreads();
  for (int u = tid; u < 16*96; u += 256){
    int l = u / 96, n = u - l*96;
    const float4* wp = (const float4*)(pw + n*96);
    const float4* ap = (const float4*)(aw + l*96);
    float acc = pb[n];
    #pragma unroll 6
    for (int k = 0; k < 24; k++){
      float4 w4 = wp[k], a4 = ap[k];
      acc += w4.x*a4.x + w4.y*a4.y + w4.z*a4.z + w4.w*a4.w;
    }
    int wt = base + l;
    int win = wt / 98, t = wt - win*98;
    int tok = src_token(win, t);
    out[(size_t)tok*192 + n] = x[(size_t)tok*192 + n] + acc;
  }
}

// ---------------- K4: LN(y1) + fc1 + GELU + fc2 + x2 add -> y2 (out[...,96:192]) ----------------
__global__ __launch_bounds__(256) void k4_mlp(const float* __restrict__ y1,
    const float* __restrict__ g2, const float* __restrict__ b2,
    const float* __restrict__ w1, const float* __restrict__ b1,
    const float* __restrict__ w2, const float* __restrict__ bb2,
    const float* __restrict__ x, float* __restrict__ out){
  __shared__ __align__(16) float yn[16*96];
  __shared__ __align__(16) float hmid[16*384];
  int tid = threadIdx.x;
  int lane = tid & 63, wv = tid >> 6;
  size_t tb = (size_t)blockIdx.x * 16;

  for (int t = wv; t < 16; t += 4){
    const float* yp = y1 + (tb + t)*192;
    float a0 = 0.f, a1 = 0.f;
    if (lane < 48){ float2 v = *(const float2*)(yp + 2*lane); a0 = v.x; a1 = v.y; }
    float s = a0+a1, s2 = a0*a0+a1*a1;
    #pragma unroll
    for (int o = 32; o; o >>= 1){ s += __shfl_xor(s,o); s2 += __shfl_xor(s2,o); }
    float mean = s*(1.f/96.f);
    float rstd = rsqrtf(s2*(1.f/96.f) - mean*mean + 1e-5f);
    if (lane < 48){
      yn[t*96 + 2*lane]   = (a0-mean)*rstd*g2[2*lane]   + b2[2*lane];
      yn[t*96 + 2*lane+1] = (a1-mean)*rstd*g2[2*lane+1] + b2[2*lane+1];
    }
  }
  __syncthreads();

  // fc1 + gelu: thread owns row n, accumulates all 16 tokens (weights read once)
  for (int n = tid; n < 384; n += 256){
    float acc[16];
    #pragma unroll
    for (int t = 0; t < 16; t++) acc[t] = 0.f;
    const float4* wp = (const float4*)(w1 + n*96);
    for (int k = 0; k < 24; k++){
      float4 w4 = wp[k];
      #pragma unroll
      for (int t = 0; t < 16; t++){
        float4 a4 = *(const float4*)(yn + t*96 + 4*k);
        acc[t] += w4.x*a4.x + w4.y*a4.y + w4.z*a4.z + w4.w*a4.w;
      }
    }
    float bias = b1[n];
    #pragma unroll
    for (int t = 0; t < 16; t++){
      float v = acc[t] + bias;
      hmid[t*384 + n] = 0.5f*v*(1.f + erff(v*0.7071067811865475f));
    }
  }
  __syncthreads();

  // fc2 split-K: threads 0..95 half 0, 96..191 half 1
  int n  = (tid < 192) ? (tid % 96) : 0;
  int ks = (tid < 192) ? (tid / 96) : 2;
  float acc[16];
  #pragma unroll
  for (int t = 0; t < 16; t++) acc[t] = 0.f;
  if (ks < 2){
    const float4* wp = (const float4*)(w2 + n*384 + ks*192);
    for (int k = 0; k < 48; k++){
      float4 w4 = wp[k];
      #pragma unroll
      for (int t = 0; t < 16; t++){
        float4 a4 = *(const float4*)(hmid + t*384 + ks*192 + 4*k);
        acc[t] += w4.x*a4.x + w4.y*a4.y + w4.z*a4.z + w4.w*a4.w;
      }
    }
  }
  __syncthreads();
  float* part = yn;          // yn is dead; reuse as partial buffer (16*96)
  if (ks == 0){
    #pragma unroll
    for (int t = 0; t < 16; t++) part[t*96 + n] = acc[t];
  }
  __syncthreads();
  if (ks == 1){
    float bias = bb2[n];
    #pragma unroll
    for (int t = 0; t < 16; t++){
      size_t tok = tb + t;
      out[tok*192 + 96 + n] = part[t*96 + n] + acc[t] + bias + x[tok*192 + 96 + n];
    }
  }
}

extern "C" void kernel_launch(void* const* d_in, const int* in_sizes, int n_in,
                              void* d_out, int out_size, void* d_ws, size_t ws_size,
                              hipStream_t stream){
  const float* x    = (const float*)d_in[0];
  const float* mask = (const float*)d_in[1];
  const int*   reli = (const int*)d_in[2];
  const float* n1g  = (const float*)d_in[3];
  const float* n1b  = (const float*)d_in[4];
  const float* qkvw = (const float*)d_in[5];
  const float* qkvb = (const float*)d_in[6];
  const float* btab = (const float*)d_in[7];
  const float* pw   = (const float*)d_in[8];
  const float* pb   = (const float*)d_in[9];
  const float* n2g  = (const float*)d_in[10];
  const float* n2b  = (const float*)d_in[11];
  const float* w1   = (const float*)d_in[12];
  const float* b1   = (const float*)d_in[13];
  const float* w2   = (const float*)d_in[14];
  const float* b2   = (const float*)d_in[15];
  float* out = (float*)d_out;

  u16* xn   = (u16*)d_ws;                       // 1024*98*96 bf16 = 18.4 MB
  u16* attn = xn + (size_t)NWIN*98*96;          // same size

  k1_ln  <<<25088, 256, 0, stream>>>(x, n1g, n1b, xn);
  k2_attn<<<3072,  256, 0, stream>>>(xn, qkvw, qkvb, btab, reli, mask, attn);
  k3_proj<<<6272,  256, 0, stream>>>(attn, pw, pb, x, out);
  k4_mlp <<<6272,  256, 0, stream>>>(out, n2g, n2b, w1, b1, w2, b2, x, out);
}

// Round 2
// 1165.577 us; speedup vs baseline: 1.8834x; 1.8834x over previous
//
#include <hip/hip_runtime.h>
#include <math.h>

typedef unsigned int u32;
typedef unsigned short u16;

typedef __attribute__((ext_vector_type(8))) short bf16x8;
typedef __attribute__((ext_vector_type(4))) float f32x4;

#define NTOK 98
#define NWIN 1024

// LDS geometry for k2 (u16 units). Strides are odd multiples of 8 u16 (16B)
// -> b128 reads down 16 rows hit 8 distinct 16B bank-granules (2-way = free).
#define XS_STR 104            // 208B = 13 granules
#define QK_STR 56             // 112B = 7 granules
#define PV_STR 136            // 272B = 17 granules
#define Q_BASE 15232          // xs/P union occupies [0, 15232)
#define K_BASE 21504
#define VT_BASE 27776
#define LDS_U16 32128         // 64256 B

__device__ __forceinline__ float bflo(u32 u){ union{u32 i; float f;} c; c.i = u<<16; return c.f; }
__device__ __forceinline__ float bfhi(u32 u){ union{u32 i; float f;} c; c.i = u & 0xffff0000u; return c.f; }
__device__ __forceinline__ u16 f2bf(float f){
  union{float f; u32 i;} c; c.f = f;
  u32 x = c.i;
  return (u16)((x + 0x7fffu + ((x>>16)&1u)) >> 16);
}

__device__ __forceinline__ int src_token(int win, int t){
  int b  = win >> 9;
  int wr = win & 511;
  int db = wr >> 6, hb = (wr >> 3) & 7, wb = wr & 7;
  int di = t / 49, r = t - di*49;
  int hi = r / 7,  wi = r - hi*7;
  int d = (db*2 + di + 1) & 15;
  int h = hb*7 + hi + 3; if (h >= 56) h -= 56;
  int w = wb*7 + wi + 3; if (w >= 56) w -= 56;
  return ((b*16 + d)*56 + h)*56 + w;
}

// ---------------- K0: preconvert qkv weights to bf16 (q rows pre-scaled) ----------------
__global__ __launch_bounds__(256) void k0_prep(const float* __restrict__ qkvw,
    const float* __restrict__ qkvb, u16* __restrict__ Wb, float* __restrict__ bs){
  int i = blockIdx.x*256 + threadIdx.x;
  if (i < 288*96){
    float v = qkvw[i];
    if (i < 96*96) v *= 0.17677669529663687f;
    Wb[i] = f2bf(v);
  }
  if (i < 288){
    float v = qkvb[i];
    if (i < 96) v *= 0.17677669529663687f;
    bs[i] = v;
  }
}

// ---------------- K1: LN(x2) + shift + window partition -> xn (bf16) ----------------
__global__ __launch_bounds__(256) void k1_ln(const float* __restrict__ x,
      const float* __restrict__ g, const float* __restrict__ bb, u16* __restrict__ xn){
  int wid  = (blockIdx.x << 2) + (threadIdx.x >> 6);
  int lane = threadIdx.x & 63;
  if (wid >= NWIN*NTOK) return;
  int win = wid / NTOK, t = wid - win*NTOK;
  int tok = src_token(win, t);
  const float* xp = x + (size_t)tok*192 + 96;
  float a0 = 0.f, a1 = 0.f;
  if (lane < 48){ float2 v = *(const float2*)(xp + (lane<<1)); a0 = v.x; a1 = v.y; }
  float s = a0 + a1, s2 = a0*a0 + a1*a1;
  #pragma unroll
  for (int o = 32; o; o >>= 1){ s += __shfl_xor(s, o); s2 += __shfl_xor(s2, o); }
  float mean = s * (1.f/96.f);
  float rstd = rsqrtf(s2*(1.f/96.f) - mean*mean + 1e-5f);
  if (lane < 48){
    float r0 = (a0-mean)*rstd*g[2*lane]   + bb[2*lane];
    float r1 = (a1-mean)*rstd*g[2*lane+1] + bb[2*lane+1];
    u32 pk = (u32)f2bf(r0) | ((u32)f2bf(r1) << 16);
    *(u32*)(xn + (size_t)wid*96 + (lane<<1)) = pk;
  }
}

// ---------------- K2: per (window, head) MFMA attention ----------------
__global__ __launch_bounds__(256) void k2_attn(const u16* __restrict__ xn,
    const u16* __restrict__ Wb, const float* __restrict__ bs,
    const float* __restrict__ bias_tab, const int* __restrict__ rel_idx,
    const float* __restrict__ mask, u16* __restrict__ attn_o){
  __shared__ __align__(16) u16 lds[LDS_U16];
  int tid  = threadIdx.x;
  int lane = tid & 63, wv = tid >> 6;
  int l15  = lane & 15, lg = lane >> 4;
  int win = blockIdx.x / 3, hd = blockIdx.x - win*3;

  // ---- stage xs (98x96 bf16, stride 104) + zero pads ----
  {
    const u32* xw = (const u32*)(xn + (size_t)win*98*96);
    u32* xs32 = (u32*)lds;                       // u32 stride 52
    for (int i = tid; i < 98*48; i += 256){
      int r = i/48, c = i - r*48;
      xs32[r*52 + c] = xw[i];
    }
    for (int i = tid; i < 14*52; i += 256){      // zero pad rows 98..111
      int r = 98 + i/52, c = i - (i/52)*52;
      xs32[r*52 + c] = 0;
    }
    u32* vt32 = (u32*)(lds + VT_BASE);           // zero vT cols 112..135
    for (int i = tid; i < 32*12; i += 256){
      int d = i/12, c = i - d*12;
      vt32[d*68 + 56 + c] = 0;
    }
  }
  __syncthreads();

  // ---- QKV GEMM: 42 tiles (q:14, k:14, vT:14), K=96 in 3 steps ----
  for (int t = wv; t < 42; t += 4){
    f32x4 acc = {0.f,0.f,0.f,0.f};
    if (t < 28){
      int tt = (t < 14) ? t : t - 14;
      int mt = tt >> 1, nt = tt & 1;
      int ch = hd*32 + nt*16 + l15 + ((t < 14) ? 0 : 96);
      const u16* wrow = Wb + ch*96 + lg*8;
      const u16* xsrow = lds + (mt*16 + l15)*XS_STR;
      #pragma unroll
      for (int ks = 0; ks < 3; ks++){
        bf16x8 a = *(const bf16x8*)(xsrow + ks*32 + lg*8);
        bf16x8 b = *(const bf16x8*)(wrow + ks*32);
        acc = __builtin_amdgcn_mfma_f32_16x16x32_bf16(a, b, acc, 0, 0, 0);
      }
      float bias = bs[ch];
      u16* dst = lds + ((t < 14) ? Q_BASE : K_BASE);
      int col = nt*16 + l15;
      int rbase = mt*16 + lg*4;
      #pragma unroll
      for (int r = 0; r < 4; r++)
        dst[(rbase+r)*QK_STR + col] = f2bf(acc[r] + bias);
    } else {
      int tt = t - 28; int mt = tt/7, nt = tt - mt*7;   // vT = Wv x xs^T
      int ch = 192 + hd*32 + mt*16 + l15;
      const u16* wrow = Wb + ch*96 + lg*8;
      const u16* xsrow = lds + (nt*16 + l15)*XS_STR;
      #pragma unroll
      for (int ks = 0; ks < 3; ks++){
        bf16x8 a = *(const bf16x8*)(wrow + ks*32);
        bf16x8 b = *(const bf16x8*)(xsrow + ks*32 + lg*8);
        acc = __builtin_amdgcn_mfma_f32_16x16x32_bf16(a, b, acc, 0, 0, 0);
      }
      int dbase = mt*16 + lg*4;
      #pragma unroll
      for (int r = 0; r < 4; r++){
        float bias = bs[192 + hd*32 + dbase + r];
        lds[VT_BASE + (dbase+r)*PV_STR + nt*16 + l15] = f2bf(acc[r] + bias);
      }
    }
  }
  __syncthreads();

  // ---- S = q k^T (in-register) + bias + mask, softmax, P -> LDS bf16 ----
  const float* mrow = mask + (size_t)(win & 511)*9604;
  for (int mt = wv; mt < 7; mt += 4){
    // zero P pad cols 112..135 for this row band (P overlays dead xs)
    {
      u32* p32 = (u32*)lds;
      for (int i = lane; i < 16*12; i += 64){
        int rr = i/12, c = i - rr*12;
        p32[(mt*16+rr)*68 + 56 + c] = 0;
      }
    }
    const u16* qrow = lds + Q_BASE + (mt*16 + l15)*QK_STR;
    bf16x8 a = *(const bf16x8*)(qrow + lg*8);
    f32x4 s[7];
    #pragma unroll
    for (int nt = 0; nt < 7; nt++){
      const u16* krow = lds + K_BASE + (nt*16 + l15)*QK_STR;
      bf16x8 b = *(const bf16x8*)(krow + lg*8);
      f32x4 z = {0.f,0.f,0.f,0.f};
      s[nt] = __builtin_amdgcn_mfma_f32_16x16x32_bf16(a, b, z, 0, 0, 0);
    }
    int ibase = mt*16 + lg*4;
    #pragma unroll
    for (int r = 0; r < 4; r++){
      int i = ibase + r;
      bool rowok = (i < 98);
      float sv[7];
      float mx = -3.0e38f;
      #pragma unroll
      for (int nt = 0; nt < 7; nt++){
        int j = nt*16 + l15;
        bool ok = rowok && (j < 98);
        int idx = ok ? (i*98 + j) : 0;
        float bm = bias_tab[rel_idx[idx]*3 + hd] + mrow[idx];
        float v = ok ? (s[nt][r] + bm) : -3.0e38f;
        sv[nt] = v;
        mx = fmaxf(mx, v);
      }
      #pragma unroll
      for (int off = 1; off < 16; off <<= 1) mx = fmaxf(mx, __shfl_xor(mx, off));
      float sum = 0.f;
      #pragma unroll
      for (int nt = 0; nt < 7; nt++){
        float e = __expf(sv[nt] - mx);
        sv[nt] = e; sum += e;
      }
      #pragma unroll
      for (int off = 1; off < 16; off <<= 1) sum += __shfl_xor(sum, off);
      float inv = 1.f / sum;
      #pragma unroll
      for (int nt = 0; nt < 7; nt++)
        lds[(size_t)i*PV_STR + nt*16 + l15] = f2bf(sv[nt]*inv);
    }
  }
  __syncthreads();

  // ---- O = P V : 14 tiles, K=128 in 4 steps ----
  for (int t = wv; t < 14; t += 4){
    int mt = t >> 1, nt = t & 1;
    const u16* prow = lds + (mt*16 + l15)*PV_STR;
    const u16* vrow = lds + VT_BASE + (nt*16 + l15)*PV_STR;
    f32x4 acc = {0.f,0.f,0.f,0.f};
    #pragma unroll
    for (int ks = 0; ks < 4; ks++){
      bf16x8 a = *(const bf16x8*)(prow + ks*32 + lg*8);
      bf16x8 b = *(const bf16x8*)(vrow + ks*32 + lg*8);
      acc = __builtin_amdgcn_mfma_f32_16x16x32_bf16(a, b, acc, 0, 0, 0);
    }
    int ibase = mt*16 + lg*4;
    int d = nt*16 + l15;
    #pragma unroll
    for (int r = 0; r < 4; r++){
      int i = ibase + r;
      if (i < 98) attn_o[((size_t)win*98 + i)*96 + hd*32 + d] = f2bf(acc[r]);
    }
  }
}

// ---------------- K3: proj + x1 add -> y1 (out[...,0:96]) ----------------
__global__ __launch_bounds__(256) void k3_proj(const u16* __restrict__ attn_o,
    const float* __restrict__ pw, const float* __restrict__ pb,
    const float* __restrict__ x, float* __restrict__ out){
  __shared__ __align__(16) float aw[16*96];
  int tid = threadIdx.x;
  int base = blockIdx.x * 16;
  const u32* src = (const u32*)(attn_o + (size_t)base*96);
  for (int i = tid; i < 16*48; i += 256){
    u32 u = src[i]; aw[2*i] = bflo(u); aw[2*i+1] = bfhi(u);
  }
  __syncthreads();
  for (int u = tid; u < 16*96; u += 256){
    int l = u / 96, n = u - l*96;
    const float4* wp = (const float4*)(pw + n*96);
    const float4* ap = (const float4*)(aw + l*96);
    float acc = pb[n];
    #pragma unroll 6
    for (int k = 0; k < 24; k++){
      float4 w4 = wp[k], a4 = ap[k];
      acc += w4.x*a4.x + w4.y*a4.y + w4.z*a4.z + w4.w*a4.w;
    }
    int wt = base + l;
    int win = wt / 98, t = wt - win*98;
    int tok = src_token(win, t);
    out[(size_t)tok*192 + n] = x[(size_t)tok*192 + n] + acc;
  }
}

// ---------------- K4: LN(y1) + fc1 + GELU + fc2 + x2 add -> y2 ----------------
__global__ __launch_bounds__(256) void k4_mlp(const float* __restrict__ y1,
    const float* __restrict__ g2, const float* __restrict__ b2,
    const float* __restrict__ w1, const float* __restrict__ b1,
    const float* __restrict__ w2, const float* __restrict__ bb2,
    const float* __restrict__ x, float* __restrict__ out){
  __shared__ __align__(16) float yn[16*96];
  __shared__ __align__(16) float hmid[16*384];
  int tid = threadIdx.x;
  int lane = tid & 63, wv = tid >> 6;
  size_t tb = (size_t)blockIdx.x * 16;

  for (int t = wv; t < 16; t += 4){
    const float* yp = y1 + (tb + t)*192;
    float a0 = 0.f, a1 = 0.f;
    if (lane < 48){ float2 v = *(const float2*)(yp + 2*lane); a0 = v.x; a1 = v.y; }
    float s = a0+a1, s2 = a0*a0+a1*a1;
    #pragma unroll
    for (int o = 32; o; o >>= 1){ s += __shfl_xor(s,o); s2 += __shfl_xor(s2,o); }
    float mean = s*(1.f/96.f);
    float rstd = rsqrtf(s2*(1.f/96.f) - mean*mean + 1e-5f);
    if (lane < 48){
      yn[t*96 + 2*lane]   = (a0-mean)*rstd*g2[2*lane]   + b2[2*lane];
      yn[t*96 + 2*lane+1] = (a1-mean)*rstd*g2[2*lane+1] + b2[2*lane+1];
    }
  }
  __syncthreads();

  for (int n = tid; n < 384; n += 256){
    float acc[16];
    #pragma unroll
    for (int t = 0; t < 16; t++) acc[t] = 0.f;
    const float4* wp = (const float4*)(w1 + n*96);
    for (int k = 0; k < 24; k++){
      float4 w4 = wp[k];
      #pragma unroll
      for (int t = 0; t < 16; t++){
        float4 a4 = *(const float4*)(yn + t*96 + 4*k);
        acc[t] += w4.x*a4.x + w4.y*a4.y + w4.z*a4.z + w4.w*a4.w;
      }
    }
    float bias = b1[n];
    #pragma unroll
    for (int t = 0; t < 16; t++){
      float v = acc[t] + bias;
      hmid[t*384 + n] = 0.5f*v*(1.f + erff(v*0.7071067811865475f));
    }
  }
  __syncthreads();

  int n  = (tid < 192) ? (tid % 96) : 0;
  int ks = (tid < 192) ? (tid / 96) : 2;
  float acc[16];
  #pragma unroll
  for (int t = 0; t < 16; t++) acc[t] = 0.f;
  if (ks < 2){
    const float4* wp = (const float4*)(w2 + n*384 + ks*192);
    for (int k = 0; k < 48; k++){
      float4 w4 = wp[k];
      #pragma unroll
      for (int t = 0; t < 16; t++){
        float4 a4 = *(const float4*)(hmid + t*384 + ks*192 + 4*k);
        acc[t] += w4.x*a4.x + w4.y*a4.y + w4.z*a4.z + w4.w*a4.w;
      }
    }
  }
  __syncthreads();
  float* part = yn;
  if (ks == 0){
    #pragma unroll
    for (int t = 0; t < 16; t++) part[t*96 + n] = acc[t];
  }
  __syncthreads();
  if (ks == 1){
    float bias = bb2[n];
    #pragma unroll
    for (int t = 0; t < 16; t++){
      size_t tok = tb + t;
      out[tok*192 + 96 + n] = part[t*96 + n] + acc[t] + bias + x[tok*192 + 96 + n];
    }
  }
}

extern "C" void kernel_launch(void* const* d_in, const int* in_sizes, int n_in,
                              void* d_out, int out_size, void* d_ws, size_t ws_size,
                              hipStream_t stream){
  const float* x    = (const float*)d_in[0];
  const float* mask = (const float*)d_in[1];
  const int*   reli = (const int*)d_in[2];
  const float* n1g  = (const float*)d_in[3];
  const float* n1b  = (const float*)d_in[4];
  const float* qkvw = (const float*)d_in[5];
  const float* qkvb = (const float*)d_in[6];
  const float* btab = (const float*)d_in[7];
  const float* pw   = (const float*)d_in[8];
  const float* pb   = (const float*)d_in[9];
  const float* n2g  = (const float*)d_in[10];
  const float* n2b  = (const float*)d_in[11];
  const float* w1   = (const float*)d_in[12];
  const float* b1   = (const float*)d_in[13];
  const float* w2   = (const float*)d_in[14];
  const float* b2   = (const float*)d_in[15];
  float* out = (float*)d_out;

  u16* xn   = (u16*)d_ws;                          // 1024*98*96 bf16
  u16* attn = xn + (size_t)NWIN*98*96;             // same size
  u16* Wb   = attn + (size_t)NWIN*98*96;           // 288*96 bf16
  float* bsc = (float*)(Wb + 288*96);              // 288 f32

  k0_prep<<<108,   256, 0, stream>>>(qkvw, qkvb, Wb, bsc);
  k1_ln  <<<25088, 256, 0, stream>>>(x, n1g, n1b, xn);
  k2_attn<<<3072,  256, 0, stream>>>(xn, Wb, bsc, btab, reli, mask, attn);
  k3_proj<<<6272,  256, 0, stream>>>(attn, pw, pb, x, out);
  k4_mlp <<<6272,  256, 0, stream>>>(out, n2g, n2b, w1, b1, w2, b2, x, out);
}

// Round 3
// 413.186 us; speedup vs baseline: 5.3128x; 2.8209x over previous
//
#include <hip/hip_runtime.h>
#include <math.h>

typedef unsigned int u32;
typedef unsigned short u16;

typedef __attribute__((ext_vector_type(8))) short bf16x8;
typedef __attribute__((ext_vector_type(4))) float f32x4;

#define NTOK 98
#define NWIN 1024

// LDS geometry for k2 (u16 units).
#define XS_STR 104
#define QK_STR 56
#define PV_STR 136
#define Q_BASE 15232
#define K_BASE 21504
#define VT_BASE 27776
#define LDS_U16 32128

__device__ __forceinline__ float bflo(u32 u){ union{u32 i; float f;} c; c.i = u<<16; return c.f; }
__device__ __forceinline__ float bfhi(u32 u){ union{u32 i; float f;} c; c.i = u & 0xffff0000u; return c.f; }
__device__ __forceinline__ u16 f2bf(float f){
  union{float f; u32 i;} c; c.f = f;
  u32 x = c.i;
  return (u16)((x + 0x7fffu + ((x>>16)&1u)) >> 16);
}

__device__ __forceinline__ int src_token(int win, int t){
  int b  = win >> 9;
  int wr = win & 511;
  int db = wr >> 6, hb = (wr >> 3) & 7, wb = wr & 7;
  int di = t / 49, r = t - di*49;
  int hi = r / 7,  wi = r - hi*7;
  int d = (db*2 + di + 1) & 15;
  int h = hb*7 + hi + 3; if (h >= 56) h -= 56;
  int w = wb*7 + wi + 3; if (w >= 56) w -= 56;
  return ((b*16 + d)*56 + h)*56 + w;
}

// ---------------- K0: preconvert all GEMM weights to bf16 ----------------
// Wb: qkv [288x96] (q pre-scaled), Pwb: [96x96], W1b: [384x96], W2b: [96x384]
__global__ __launch_bounds__(256) void k0_prep(const float* __restrict__ qkvw,
    const float* __restrict__ qkvb, const float* __restrict__ pw,
    const float* __restrict__ w1, const float* __restrict__ w2,
    u16* __restrict__ Wb, float* __restrict__ bs){
  int i = blockIdx.x*256 + threadIdx.x;
  if (i < 288*96){
    float v = qkvw[i];
    if (i < 96*96) v *= 0.17677669529663687f;
    Wb[i] = f2bf(v);
  } else if (i < 288*96 + 96*96){
    Wb[i] = f2bf(pw[i - 288*96]);
  } else if (i < 288*96 + 96*96 + 384*96){
    Wb[i] = f2bf(w1[i - (288*96 + 96*96)]);
  } else if (i < 288*96 + 96*96 + 384*96 + 96*384){
    Wb[i] = f2bf(w2[i - (288*96 + 96*96 + 384*96)]);
  }
  if (i < 288){
    float v = qkvb[i];
    if (i < 96) v *= 0.17677669529663687f;
    bs[i] = v;
  }
}

// ---------------- K1: LN(x2) + shift + window partition -> xn (bf16) ----------------
__global__ __launch_bounds__(256) void k1_ln(const float* __restrict__ x,
      const float* __restrict__ g, const float* __restrict__ bb, u16* __restrict__ xn){
  int wid  = (blockIdx.x << 2) + (threadIdx.x >> 6);
  int lane = threadIdx.x & 63;
  if (wid >= NWIN*NTOK) return;
  int win = wid / NTOK, t = wid - win*NTOK;
  int tok = src_token(win, t);
  const float* xp = x + (size_t)tok*192 + 96;
  float a0 = 0.f, a1 = 0.f;
  if (lane < 48){ float2 v = *(const float2*)(xp + (lane<<1)); a0 = v.x; a1 = v.y; }
  float s = a0 + a1, s2 = a0*a0 + a1*a1;
  #pragma unroll
  for (int o = 32; o; o >>= 1){ s += __shfl_xor(s, o); s2 += __shfl_xor(s2, o); }
  float mean = s * (1.f/96.f);
  float rstd = rsqrtf(s2*(1.f/96.f) - mean*mean + 1e-5f);
  if (lane < 48){
    float r0 = (a0-mean)*rstd*g[2*lane]   + bb[2*lane];
    float r1 = (a1-mean)*rstd*g[2*lane+1] + bb[2*lane+1];
    u32 pk = (u32)f2bf(r0) | ((u32)f2bf(r1) << 16);
    *(u32*)(xn + (size_t)wid*96 + (lane<<1)) = pk;
  }
}

// ---------------- K2: per (window, head) MFMA attention ----------------
__global__ __launch_bounds__(256) void k2_attn(const u16* __restrict__ xn,
    const u16* __restrict__ Wb, const float* __restrict__ bs,
    const float* __restrict__ bias_tab, const int* __restrict__ rel_idx,
    const float* __restrict__ mask, u16* __restrict__ attn_o){
  __shared__ __align__(16) u16 lds[LDS_U16];
  int tid  = threadIdx.x;
  int lane = tid & 63, wv = tid >> 6;
  int l15  = lane & 15, lg = lane >> 4;
  int win = blockIdx.x / 3, hd = blockIdx.x - win*3;

  {
    const u32* xw = (const u32*)(xn + (size_t)win*98*96);
    u32* xs32 = (u32*)lds;
    for (int i = tid; i < 98*48; i += 256){
      int r = i/48, c = i - r*48;
      xs32[r*52 + c] = xw[i];
    }
    for (int i = tid; i < 14*52; i += 256){
      int r = 98 + i/52, c = i - (i/52)*52;
      xs32[r*52 + c] = 0;
    }
    u32* vt32 = (u32*)(lds + VT_BASE);
    for (int i = tid; i < 32*12; i += 256){
      int d = i/12, c = i - d*12;
      vt32[d*68 + 56 + c] = 0;
    }
  }
  __syncthreads();

  for (int t = wv; t < 42; t += 4){
    f32x4 acc = {0.f,0.f,0.f,0.f};
    if (t < 28){
      int tt = (t < 14) ? t : t - 14;
      int mt = tt >> 1, nt = tt & 1;
      int ch = hd*32 + nt*16 + l15 + ((t < 14) ? 0 : 96);
      const u16* wrow = Wb + ch*96 + lg*8;
      const u16* xsrow = lds + (mt*16 + l15)*XS_STR;
      #pragma unroll
      for (int ks = 0; ks < 3; ks++){
        bf16x8 a = *(const bf16x8*)(xsrow + ks*32 + lg*8);
        bf16x8 b = *(const bf16x8*)(wrow + ks*32);
        acc = __builtin_amdgcn_mfma_f32_16x16x32_bf16(a, b, acc, 0, 0, 0);
      }
      float bias = bs[ch];
      u16* dst = lds + ((t < 14) ? Q_BASE : K_BASE);
      int col = nt*16 + l15;
      int rbase = mt*16 + lg*4;
      #pragma unroll
      for (int r = 0; r < 4; r++)
        dst[(rbase+r)*QK_STR + col] = f2bf(acc[r] + bias);
    } else {
      int tt = t - 28; int mt = tt/7, nt = tt - mt*7;
      int ch = 192 + hd*32 + mt*16 + l15;
      const u16* wrow = Wb + ch*96 + lg*8;
      const u16* xsrow = lds + (nt*16 + l15)*XS_STR;
      #pragma unroll
      for (int ks = 0; ks < 3; ks++){
        bf16x8 a = *(const bf16x8*)(wrow + ks*32);
        bf16x8 b = *(const bf16x8*)(xsrow + ks*32 + lg*8);
        acc = __builtin_amdgcn_mfma_f32_16x16x32_bf16(a, b, acc, 0, 0, 0);
      }
      int dbase = mt*16 + lg*4;
      #pragma unroll
      for (int r = 0; r < 4; r++){
        float bias = bs[192 + hd*32 + dbase + r];
        lds[VT_BASE + (dbase+r)*PV_STR + nt*16 + l15] = f2bf(acc[r] + bias);
      }
    }
  }
  __syncthreads();

  const float* mrow = mask + (size_t)(win & 511)*9604;
  for (int mt = wv; mt < 7; mt += 4){
    {
      u32* p32 = (u32*)lds;
      for (int i = lane; i < 16*12; i += 64){
        int rr = i/12, c = i - rr*12;
        p32[(mt*16+rr)*68 + 56 + c] = 0;
      }
    }
    const u16* qrow = lds + Q_BASE + (mt*16 + l15)*QK_STR;
    bf16x8 a = *(const bf16x8*)(qrow + lg*8);
    f32x4 s[7];
    #pragma unroll
    for (int nt = 0; nt < 7; nt++){
      const u16* krow = lds + K_BASE + (nt*16 + l15)*QK_STR;
      bf16x8 b = *(const bf16x8*)(krow + lg*8);
      f32x4 z = {0.f,0.f,0.f,0.f};
      s[nt] = __builtin_amdgcn_mfma_f32_16x16x32_bf16(a, b, z, 0, 0, 0);
    }
    int ibase = mt*16 + lg*4;
    #pragma unroll
    for (int r = 0; r < 4; r++){
      int i = ibase + r;
      bool rowok = (i < 98);
      float sv[7];
      float mx = -3.0e38f;
      #pragma unroll
      for (int nt = 0; nt < 7; nt++){
        int j = nt*16 + l15;
        bool ok = rowok && (j < 98);
        int idx = ok ? (i*98 + j) : 0;
        float bm = bias_tab[rel_idx[idx]*3 + hd] + mrow[idx];
        float v = ok ? (s[nt][r] + bm) : -3.0e38f;
        sv[nt] = v;
        mx = fmaxf(mx, v);
      }
      #pragma unroll
      for (int off = 1; off < 16; off <<= 1) mx = fmaxf(mx, __shfl_xor(mx, off));
      float sum = 0.f;
      #pragma unroll
      for (int nt = 0; nt < 7; nt++){
        float e = __expf(sv[nt] - mx);
        sv[nt] = e; sum += e;
      }
      #pragma unroll
      for (int off = 1; off < 16; off <<= 1) sum += __shfl_xor(sum, off);
      float inv = 1.f / sum;
      #pragma unroll
      for (int nt = 0; nt < 7; nt++)
        lds[(size_t)i*PV_STR + nt*16 + l15] = f2bf(sv[nt]*inv);
    }
  }
  __syncthreads();

  for (int t = wv; t < 14; t += 4){
    int mt = t >> 1, nt = t & 1;
    const u16* prow = lds + (mt*16 + l15)*PV_STR;
    const u16* vrow = lds + VT_BASE + (nt*16 + l15)*PV_STR;
    f32x4 acc = {0.f,0.f,0.f,0.f};
    #pragma unroll
    for (int ks = 0; ks < 4; ks++){
      bf16x8 a = *(const bf16x8*)(prow + ks*32 + lg*8);
      bf16x8 b = *(const bf16x8*)(vrow + ks*32 + lg*8);
      acc = __builtin_amdgcn_mfma_f32_16x16x32_bf16(a, b, acc, 0, 0, 0);
    }
    int ibase = mt*16 + lg*4;
    int d = nt*16 + l15;
    #pragma unroll
    for (int r = 0; r < 4; r++){
      int i = ibase + r;
      if (i < 98) attn_o[((size_t)win*98 + i)*96 + hd*32 + d] = f2bf(acc[r]);
    }
  }
}

// ---------------- K3: MFMA proj + x1 add -> y1 (out[...,0:96]) ----------------
__global__ __launch_bounds__(256) void k3_proj(const u16* __restrict__ attn_o,
    const u16* __restrict__ Pwb, const float* __restrict__ pb,
    const float* __restrict__ x, float* __restrict__ out){
  __shared__ __align__(16) u16 aw[64*104];
  int tid = threadIdx.x;
  int lane = tid & 63, wv = tid >> 6;
  int l15 = lane & 15, lg = lane >> 4;
  size_t base = (size_t)blockIdx.x * 64;

  const u32* src = (const u32*)(attn_o + base*96);
  u32* aw32 = (u32*)aw;
  for (int i = tid; i < 64*48; i += 256){
    int r = i/48, c = i - r*48;
    aw32[r*52 + c] = src[i];
  }
  __syncthreads();

  const u16* arow = aw + (wv*16 + l15)*104 + lg*8;
  bf16x8 a0 = *(const bf16x8*)(arow);
  bf16x8 a1 = *(const bf16x8*)(arow + 32);
  bf16x8 a2 = *(const bf16x8*)(arow + 64);

  #pragma unroll
  for (int nt = 0; nt < 6; nt++){
    const u16* wrow = Pwb + (nt*16 + l15)*96 + lg*8;
    f32x4 acc = {0.f,0.f,0.f,0.f};
    acc = __builtin_amdgcn_mfma_f32_16x16x32_bf16(a0, *(const bf16x8*)(wrow),      acc, 0, 0, 0);
    acc = __builtin_amdgcn_mfma_f32_16x16x32_bf16(a1, *(const bf16x8*)(wrow + 32), acc, 0, 0, 0);
    acc = __builtin_amdgcn_mfma_f32_16x16x32_bf16(a2, *(const bf16x8*)(wrow + 64), acc, 0, 0, 0);
    int n = nt*16 + l15;
    float bias = pb[n];
    #pragma unroll
    for (int r = 0; r < 4; r++){
      int wt = (int)base + wv*16 + lg*4 + r;
      int win = wt / 98, t = wt - win*98;
      int tok = src_token(win, t);
      out[(size_t)tok*192 + n] = x[(size_t)tok*192 + n] + acc[r] + bias;
    }
  }
}

// ---------------- K4: MFMA MLP: LN(y1)+fc1+GELU+fc2+x2 -> out[...,96:192] ----------------
#define HS 392
__global__ __launch_bounds__(256) void k4_mlp(const float* __restrict__ y1,
    const float* __restrict__ g2, const float* __restrict__ b2,
    const u16* __restrict__ W1b, const float* __restrict__ b1,
    const u16* __restrict__ W2b, const float* __restrict__ bb2,
    const float* __restrict__ x, float* __restrict__ out){
  __shared__ __align__(16) u16 yn[64*104];
  __shared__ __align__(16) u16 H[64*HS];
  int tid = threadIdx.x;
  int lane = tid & 63, wv = tid >> 6;
  int l15 = lane & 15, lg = lane >> 4;
  size_t tb = (size_t)blockIdx.x * 64;
  int myrow = wv*16 + l15;

  // ---- A: LN -> yn (bf16). 4 threads per token (lg = quarter), 16 tokens per wave.
  {
    const float4* yp = (const float4*)(y1 + (tb + myrow)*192 + lg*24);
    float4 v4[6];
    #pragma unroll
    for (int j = 0; j < 6; j++) v4[j] = yp[j];
    float s = 0.f, s2 = 0.f;
    #pragma unroll
    for (int j = 0; j < 6; j++){
      s  += v4[j].x + v4[j].y + v4[j].z + v4[j].w;
      s2 += v4[j].x*v4[j].x + v4[j].y*v4[j].y + v4[j].z*v4[j].z + v4[j].w*v4[j].w;
    }
    s  += __shfl_xor(s, 16);  s  += __shfl_xor(s, 32);
    s2 += __shfl_xor(s2, 16); s2 += __shfl_xor(s2, 32);
    float mean = s * (1.f/96.f);
    float rstd = rsqrtf(s2*(1.f/96.f) - mean*mean + 1e-5f);
    u32* dst = (u32*)(yn + myrow*104) + lg*12;
    const float* gp = g2 + lg*24;
    const float* bp = b2 + lg*24;
    #pragma unroll
    for (int p = 0; p < 12; p++){
      float e0 = (p & 1) ? v4[p>>1].z : v4[p>>1].x;
      float e1 = (p & 1) ? v4[p>>1].w : v4[p>>1].y;
      float r0 = (e0 - mean)*rstd*gp[2*p]   + bp[2*p];
      float r1 = (e1 - mean)*rstd*gp[2*p+1] + bp[2*p+1];
      dst[p] = (u32)f2bf(r0) | ((u32)f2bf(r1) << 16);
    }
  }
  __syncthreads();

  // ---- B: fc1 + GELU -> H (bf16). wave owns m-tile = wv; 24 n-tiles.
  {
    const u16* arow = yn + myrow*104 + lg*8;
    bf16x8 a0 = *(const bf16x8*)(arow);
    bf16x8 a1 = *(const bf16x8*)(arow + 32);
    bf16x8 a2 = *(const bf16x8*)(arow + 64);
    #pragma unroll 4
    for (int nt = 0; nt < 24; nt++){
      const u16* wrow = W1b + (nt*16 + l15)*96 + lg*8;
      f32x4 acc = {0.f,0.f,0.f,0.f};
      acc = __builtin_amdgcn_mfma_f32_16x16x32_bf16(a0, *(const bf16x8*)(wrow),      acc, 0, 0, 0);
      acc = __builtin_amdgcn_mfma_f32_16x16x32_bf16(a1, *(const bf16x8*)(wrow + 32), acc, 0, 0, 0);
      acc = __builtin_amdgcn_mfma_f32_16x16x32_bf16(a2, *(const bf16x8*)(wrow + 64), acc, 0, 0, 0);
      int n = nt*16 + l15;
      float bias = b1[n];
      #pragma unroll
      for (int r = 0; r < 4; r++){
        float v = acc[r] + bias;
        float h = 0.5f*v*(1.f + erff(v*0.7071067811865475f));
        H[(wv*16 + lg*4 + r)*HS + n] = f2bf(h);
      }
    }
  }
  __syncthreads();

  // ---- C: fc2 + bias + residual -> out. wave owns m-tile = wv; 6 n-tiles, K=384.
  {
    const u16* arow = H + myrow*HS + lg*8;
    bf16x8 ar[12];
    #pragma unroll
    for (int ks = 0; ks < 12; ks++) ar[ks] = *(const bf16x8*)(arow + ks*32);
    #pragma unroll
    for (int nt = 0; nt < 6; nt++){
      const u16* wrow = W2b + (nt*16 + l15)*384 + lg*8;
      f32x4 acc = {0.f,0.f,0.f,0.f};
      #pragma unroll
      for (int ks = 0; ks < 12; ks++)
        acc = __builtin_amdgcn_mfma_f32_16x16x32_bf16(ar[ks], *(const bf16x8*)(wrow + ks*32), acc, 0, 0, 0);
      int c = nt*16 + l15;
      float bias = bb2[c];
      #pragma unroll
      for (int r = 0; r < 4; r++){
        size_t tok = tb + wv*16 + lg*4 + r;
        out[tok*192 + 96 + c] = x[tok*192 + 96 + c] + acc[r] + bias;
      }
    }
  }
}

extern "C" void kernel_launch(void* const* d_in, const int* in_sizes, int n_in,
                              void* d_out, int out_size, void* d_ws, size_t ws_size,
                              hipStream_t stream){
  const float* x    = (const float*)d_in[0];
  const float* mask = (const float*)d_in[1];
  const int*   reli = (const int*)d_in[2];
  const float* n1g  = (const float*)d_in[3];
  const float* n1b  = (const float*)d_in[4];
  const float* qkvw = (const float*)d_in[5];
  const float* qkvb = (const float*)d_in[6];
  const float* btab = (const float*)d_in[7];
  const float* pw   = (const float*)d_in[8];
  const float* pb   = (const float*)d_in[9];
  const float* n2g  = (const float*)d_in[10];
  const float* n2b  = (const float*)d_in[11];
  const float* w1   = (const float*)d_in[12];
  const float* b1   = (const float*)d_in[13];
  const float* w2   = (const float*)d_in[14];
  const float* b2   = (const float*)d_in[15];
  float* out = (float*)d_out;

  u16* xn   = (u16*)d_ws;                          // 1024*98*96 bf16
  u16* attn = xn + (size_t)NWIN*98*96;
  u16* Wb   = attn + (size_t)NWIN*98*96;           // qkv 288*96
  u16* Pwb  = Wb + 288*96;                         // 96*96
  u16* W1b  = Pwb + 96*96;                         // 384*96
  u16* W2b  = W1b + 384*96;                        // 96*384
  float* bsc = (float*)(W2b + 96*384);             // 288 f32

  k0_prep<<<432,   256, 0, stream>>>(qkvw, qkvb, pw, w1, w2, Wb, bsc);
  k1_ln  <<<25088, 256, 0, stream>>>(x, n1g, n1b, xn);
  k2_attn<<<3072,  256, 0, stream>>>(xn, Wb, bsc, btab, reli, mask, attn);
  k3_proj<<<1568,  256, 0, stream>>>(attn, Pwb, pb, x, out);
  k4_mlp <<<1568,  256, 0, stream>>>(out, n2g, n2b, W1b, b1, W2b, b2, x, out);
}

// Round 4
// 242.456 us; speedup vs baseline: 9.0540x; 1.7042x over previous
//
#include <hip/hip_runtime.h>
#include <math.h>

typedef unsigned int u32;
typedef unsigned short u16;

typedef __attribute__((ext_vector_type(8))) short bf16x8;
typedef __attribute__((ext_vector_type(4))) float f32x4;

#define NTOK 98
#define NWIN 1024

// LDS geometry for k2 (u16 units). Total 26640 u16 = 53280 B -> 3 blocks/CU.
#define XS_STR 104            // xs: 208B rows (13 granules, odd -> conflict-free b128)
#define QK_STR 40             // q/k: 80B rows (5 granules, odd)
#define P_STR  136            // P/vT: 272B rows (17 granules, odd)
#define Q_BASE 13328          // xs/P union occupies [0, 13328)
#define K_BASE 17808
#define VT_BASE 22288
#define LDS_U16 26640

__device__ __forceinline__ float bflo(u32 u){ union{u32 i; float f;} c; c.i = u<<16; return c.f; }
__device__ __forceinline__ float bfhi(u32 u){ union{u32 i; float f;} c; c.i = u & 0xffff0000u; return c.f; }
__device__ __forceinline__ u16 f2bf(float f){
  union{float f; u32 i;} c; c.f = f;
  u32 x = c.i;
  return (u16)((x + 0x7fffu + ((x>>16)&1u)) >> 16);
}

__device__ __forceinline__ int src_token(int win, int t){
  int b  = win >> 9;
  int wr = win & 511;
  int db = wr >> 6, hb = (wr >> 3) & 7, wb = wr & 7;
  int di = t / 49, r = t - di*49;
  int hi = r / 7,  wi = r - hi*7;
  int d = (db*2 + di + 1) & 15;
  int h = hb*7 + hi + 3; if (h >= 56) h -= 56;
  int w = wb*7 + wi + 3; if (w >= 56) w -= 56;
  return ((b*16 + d)*56 + h)*56 + w;
}

// ---------------- K0: preconvert all GEMM weights to bf16 ----------------
__global__ __launch_bounds__(256) void k0_prep(const float* __restrict__ qkvw,
    const float* __restrict__ qkvb, const float* __restrict__ pw,
    const float* __restrict__ w1, const float* __restrict__ w2,
    u16* __restrict__ Wb, float* __restrict__ bs){
  int i = blockIdx.x*256 + threadIdx.x;
  if (i < 288*96){
    float v = qkvw[i];
    if (i < 96*96) v *= 0.17677669529663687f;
    Wb[i] = f2bf(v);
  } else if (i < 288*96 + 96*96){
    Wb[i] = f2bf(pw[i - 288*96]);
  } else if (i < 288*96 + 96*96 + 384*96){
    Wb[i] = f2bf(w1[i - (288*96 + 96*96)]);
  } else if (i < 288*96 + 96*96 + 384*96 + 96*384){
    Wb[i] = f2bf(w2[i - (288*96 + 96*96 + 384*96)]);
  }
  if (i < 288){
    float v = qkvb[i];
    if (i < 96) v *= 0.17677669529663687f;
    bs[i] = v;
  }
}

// ---------------- K0b: comb[m][hd][112][112] = rel_bias + mask (8 distinct patterns) ----------------
__global__ __launch_bounds__(256) void k0b_comb(const float* __restrict__ bias_tab,
    const int* __restrict__ rel_idx, const float* __restrict__ mask,
    float* __restrict__ comb){
  int idx = blockIdx.x*256 + threadIdx.x;
  if (idx >= 8*3*112*112) return;
  int m  = idx / 37632; int r1 = idx - m*37632;
  int hd = r1 / 12544;  int r2 = r1 - hd*12544;
  int i  = r2 / 112,    j  = r2 - i*112;
  float v = -1e30f;
  if (i < 98 && j < 98){
    int wr = ((m>>2)&1)*448 + ((m>>1)&1)*56 + (m&1)*7;   // representative window
    v = bias_tab[rel_idx[i*98+j]*3 + hd] + mask[(size_t)wr*9604 + i*98 + j];
  }
  comb[idx] = v;
}

// ---------------- K1: LN(x2) + shift + window partition -> xn (bf16) ----------------
__global__ __launch_bounds__(256) void k1_ln(const float* __restrict__ x,
      const float* __restrict__ g, const float* __restrict__ bb, u16* __restrict__ xn){
  int wid  = (blockIdx.x << 2) + (threadIdx.x >> 6);
  int lane = threadIdx.x & 63;
  if (wid >= NWIN*NTOK) return;
  int win = wid / NTOK, t = wid - win*NTOK;
  int tok = src_token(win, t);
  const float* xp = x + (size_t)tok*192 + 96;
  float a0 = 0.f, a1 = 0.f;
  if (lane < 48){ float2 v = *(const float2*)(xp + (lane<<1)); a0 = v.x; a1 = v.y; }
  float s = a0 + a1, s2 = a0*a0 + a1*a1;
  #pragma unroll
  for (int o = 32; o; o >>= 1){ s += __shfl_xor(s, o); s2 += __shfl_xor(s2, o); }
  float mean = s * (1.f/96.f);
  float rstd = rsqrtf(s2*(1.f/96.f) - mean*mean + 1e-5f);
  if (lane < 48){
    float r0 = (a0-mean)*rstd*g[2*lane]   + bb[2*lane];
    float r1 = (a1-mean)*rstd*g[2*lane+1] + bb[2*lane+1];
    u32 pk = (u32)f2bf(r0) | ((u32)f2bf(r1) << 16);
    *(u32*)(xn + (size_t)wid*96 + (lane<<1)) = pk;
  }
}

// ---------------- K2: per (window, head) MFMA attention ----------------
__global__ __launch_bounds__(256) void k2_attn(const u16* __restrict__ xn,
    const u16* __restrict__ Wb, const float* __restrict__ bs,
    const float* __restrict__ comb, u16* __restrict__ attn_o){
  __shared__ __align__(16) u16 lds[LDS_U16];
  int tid  = threadIdx.x;
  int lane = tid & 63, wv = tid >> 6;
  int l15  = lane & 15, lg = lane >> 4;
  int win = blockIdx.x / 3, hd = blockIdx.x - win*3;

  // ---- stage xs (98x96 bf16, stride 104) + zero pad rows 98..111 ----
  {
    const u32* xw = (const u32*)(xn + (size_t)win*98*96);
    u32* xs32 = (u32*)lds;
    for (int i = tid; i < 98*48; i += 256){
      int r = i/48, c = i - r*48;
      xs32[r*52 + c] = xw[i];
    }
    for (int i = tid; i < 14*52; i += 256){
      int r = 98 + i/52, c = i - (i/52)*52;
      xs32[r*52 + c] = 0;
    }
    u32* vt32 = (u32*)(lds + VT_BASE);           // zero vT pad cols 112..135
    for (int i = tid; i < 32*12; i += 256){
      int d = i/12, c = i - d*12;
      vt32[d*68 + 56 + c] = 0;
    }
  }
  __syncthreads();

  // ---- QKV GEMM: 42 tiles (q:14, k:14, vT:14), K=96 in 3 steps ----
  for (int t = wv; t < 42; t += 4){
    f32x4 acc = {0.f,0.f,0.f,0.f};
    if (t < 28){
      int tt = (t < 14) ? t : t - 14;
      int mt = tt >> 1, nt = tt & 1;
      int ch = hd*32 + nt*16 + l15 + ((t < 14) ? 0 : 96);
      const u16* wrow = Wb + ch*96 + lg*8;
      const u16* xsrow = lds + (mt*16 + l15)*XS_STR;
      #pragma unroll
      for (int ks = 0; ks < 3; ks++){
        bf16x8 a = *(const bf16x8*)(xsrow + ks*32 + lg*8);
        bf16x8 b = *(const bf16x8*)(wrow + ks*32);
        acc = __builtin_amdgcn_mfma_f32_16x16x32_bf16(a, b, acc, 0, 0, 0);
      }
      float bias = bs[ch];
      u16* dst = lds + ((t < 14) ? Q_BASE : K_BASE);
      int col = nt*16 + l15;
      int rbase = mt*16 + lg*4;
      #pragma unroll
      for (int r = 0; r < 4; r++)
        dst[(rbase+r)*QK_STR + col] = f2bf(acc[r] + bias);
    } else {
      int tt = t - 28; int mt = tt/7, nt = tt - mt*7;   // vT = Wv x xs^T
      int ch = 192 + hd*32 + mt*16 + l15;
      const u16* wrow = Wb + ch*96 + lg*8;
      const u16* xsrow = lds + (nt*16 + l15)*XS_STR;
      #pragma unroll
      for (int ks = 0; ks < 3; ks++){
        bf16x8 a = *(const bf16x8*)(wrow + ks*32);
        bf16x8 b = *(const bf16x8*)(xsrow + ks*32 + lg*8);
        acc = __builtin_amdgcn_mfma_f32_16x16x32_bf16(a, b, acc, 0, 0, 0);
      }
      int dbase = mt*16 + lg*4;
      #pragma unroll
      for (int r = 0; r < 4; r++){
        float bias = bs[192 + hd*32 + dbase + r];
        lds[VT_BASE + (dbase+r)*P_STR + nt*16 + l15] = f2bf(acc[r] + bias);
      }
    }
  }
  __syncthreads();

  // ---- S = q k^T + comb (preloaded), softmax, P -> LDS bf16 (overlays dead xs) ----
  {
    int wr = win & 511;
    int maskid = ((wr>>6)==7)*4 + (((wr>>3)&7)==7)*2 + ((wr&7)==7);
    const float* cb_base = comb + (size_t)(maskid*3 + hd)*12544 + l15;

    for (int mt = wv; mt < 7; mt += 4){
      // zero P pad cols 112..135 (valid rows of this band only)
      {
        u32* p32 = (u32*)lds;
        int rmax = (mt == 6) ? 2 : 16;
        for (int i = lane; i < rmax*12; i += 64){
          int rr = i/12, c = i - rr*12;
          p32[(mt*16+rr)*68 + 56 + c] = 0;
        }
      }
      int ibase = mt*16 + lg*4;
      // hoist comb loads (independent of MFMA)
      float cb[4][7];
      #pragma unroll
      for (int r = 0; r < 4; r++){
        const float* cbp = cb_base + (ibase + r)*112;
        #pragma unroll
        for (int nt = 0; nt < 7; nt++) cb[r][nt] = cbp[nt*16];
      }
      const u16* qrow = lds + Q_BASE + (mt*16 + l15)*QK_STR;
      bf16x8 a = *(const bf16x8*)(qrow + lg*8);
      f32x4 s[7];
      #pragma unroll
      for (int nt = 0; nt < 7; nt++){
        const u16* krow = lds + K_BASE + (nt*16 + l15)*QK_STR;
        bf16x8 b = *(const bf16x8*)(krow + lg*8);
        f32x4 z = {0.f,0.f,0.f,0.f};
        s[nt] = __builtin_amdgcn_mfma_f32_16x16x32_bf16(a, b, z, 0, 0, 0);
      }
      #pragma unroll
      for (int r = 0; r < 4; r++){
        int i = ibase + r;
        float sv[7];
        float mx = -3.0e38f;
        #pragma unroll
        for (int nt = 0; nt < 7; nt++){
          float v = s[nt][r] + cb[r][nt];
          sv[nt] = v; mx = fmaxf(mx, v);
        }
        #pragma unroll
        for (int off = 1; off < 16; off <<= 1) mx = fmaxf(mx, __shfl_xor(mx, off));
        float sum = 0.f;
        #pragma unroll
        for (int nt = 0; nt < 7; nt++){
          float e = __expf(sv[nt] - mx);
          sv[nt] = e; sum += e;
        }
        #pragma unroll
        for (int off = 1; off < 16; off <<= 1) sum += __shfl_xor(sum, off);
        float inv = 1.f / sum;
        if (i < 98){
          #pragma unroll
          for (int nt = 0; nt < 7; nt++)
            lds[i*P_STR + nt*16 + l15] = f2bf(sv[nt]*inv);
        }
      }
    }
  }
  __syncthreads();

  // ---- O = P V : 14 tiles, K=128 in 4 steps ----
  for (int t = wv; t < 14; t += 4){
    int mt = t >> 1, nt = t & 1;
    const u16* prow = lds + (mt*16 + l15)*P_STR;
    const u16* vrow = lds + VT_BASE + (nt*16 + l15)*P_STR;
    f32x4 acc = {0.f,0.f,0.f,0.f};
    #pragma unroll
    for (int ks = 0; ks < 4; ks++){
      bf16x8 a = *(const bf16x8*)(prow + ks*32 + lg*8);
      bf16x8 b = *(const bf16x8*)(vrow + ks*32 + lg*8);
      acc = __builtin_amdgcn_mfma_f32_16x16x32_bf16(a, b, acc, 0, 0, 0);
    }
    int ibase = mt*16 + lg*4;
    int d = nt*16 + l15;
    #pragma unroll
    for (int r = 0; r < 4; r++){
      int i = ibase + r;
      if (i < 98) attn_o[((size_t)win*98 + i)*96 + hd*32 + d] = f2bf(acc[r]);
    }
  }
}

// ---------------- K3: MFMA proj + x1 add -> y1 (out[...,0:96]) ----------------
__global__ __launch_bounds__(256) void k3_proj(const u16* __restrict__ attn_o,
    const u16* __restrict__ Pwb, const float* __restrict__ pb,
    const float* __restrict__ x, float* __restrict__ out){
  __shared__ __align__(16) u16 aw[64*104];
  int tid = threadIdx.x;
  int lane = tid & 63, wv = tid >> 6;
  int l15 = lane & 15, lg = lane >> 4;
  size_t base = (size_t)blockIdx.x * 64;

  const u32* src = (const u32*)(attn_o + base*96);
  u32* aw32 = (u32*)aw;
  for (int i = tid; i < 64*48; i += 256){
    int r = i/48, c = i - r*48;
    aw32[r*52 + c] = src[i];
  }
  __syncthreads();

  const u16* arow = aw + (wv*16 + l15)*104 + lg*8;
  bf16x8 a0 = *(const bf16x8*)(arow);
  bf16x8 a1 = *(const bf16x8*)(arow + 32);
  bf16x8 a2 = *(const bf16x8*)(arow + 64);

  #pragma unroll
  for (int nt = 0; nt < 6; nt++){
    const u16* wrow = Pwb + (nt*16 + l15)*96 + lg*8;
    f32x4 acc = {0.f,0.f,0.f,0.f};
    acc = __builtin_amdgcn_mfma_f32_16x16x32_bf16(a0, *(const bf16x8*)(wrow),      acc, 0, 0, 0);
    acc = __builtin_amdgcn_mfma_f32_16x16x32_bf16(a1, *(const bf16x8*)(wrow + 32), acc, 0, 0, 0);
    acc = __builtin_amdgcn_mfma_f32_16x16x32_bf16(a2, *(const bf16x8*)(wrow + 64), acc, 0, 0, 0);
    int n = nt*16 + l15;
    float bias = pb[n];
    #pragma unroll
    for (int r = 0; r < 4; r++){
      int wt = (int)base + wv*16 + lg*4 + r;
      int win = wt / 98, t = wt - win*98;
      int tok = src_token(win, t);
      out[(size_t)tok*192 + n] = x[(size_t)tok*192 + n] + acc[r] + bias;
    }
  }
}

// ---------------- K4: MFMA MLP: LN(y1)+fc1+GELU+fc2+x2 -> out[...,96:192] ----------------
#define HS 392
__global__ __launch_bounds__(256) void k4_mlp(const float* __restrict__ y1,
    const float* __restrict__ g2, const float* __restrict__ b2,
    const u16* __restrict__ W1b, const float* __restrict__ b1,
    const u16* __restrict__ W2b, const float* __restrict__ bb2,
    const float* __restrict__ x, float* __restrict__ out){
  __shared__ __align__(16) u16 yn[64*104];
  __shared__ __align__(16) u16 H[64*HS];
  int tid = threadIdx.x;
  int lane = tid & 63, wv = tid >> 6;
  int l15 = lane & 15, lg = lane >> 4;
  size_t tb = (size_t)blockIdx.x * 64;
  int myrow = wv*16 + l15;

  {
    const float4* yp = (const float4*)(y1 + (tb + myrow)*192 + lg*24);
    float4 v4[6];
    #pragma unroll
    for (int j = 0; j < 6; j++) v4[j] = yp[j];
    float s = 0.f, s2 = 0.f;
    #pragma unroll
    for (int j = 0; j < 6; j++){
      s  += v4[j].x + v4[j].y + v4[j].z + v4[j].w;
      s2 += v4[j].x*v4[j].x + v4[j].y*v4[j].y + v4[j].z*v4[j].z + v4[j].w*v4[j].w;
    }
    s  += __shfl_xor(s, 16);  s  += __shfl_xor(s, 32);
    s2 += __shfl_xor(s2, 16); s2 += __shfl_xor(s2, 32);
    float mean = s * (1.f/96.f);
    float rstd = rsqrtf(s2*(1.f/96.f) - mean*mean + 1e-5f);
    u32* dst = (u32*)(yn + myrow*104) + lg*12;
    const float* gp = g2 + lg*24;
    const float* bp = b2 + lg*24;
    #pragma unroll
    for (int p = 0; p < 12; p++){
      float e0 = (p & 1) ? v4[p>>1].z : v4[p>>1].x;
      float e1 = (p & 1) ? v4[p>>1].w : v4[p>>1].y;
      float r0 = (e0 - mean)*rstd*gp[2*p]   + bp[2*p];
      float r1 = (e1 - mean)*rstd*gp[2*p+1] + bp[2*p+1];
      dst[p] = (u32)f2bf(r0) | ((u32)f2bf(r1) << 16);
    }
  }
  __syncthreads();

  {
    const u16* arow = yn + myrow*104 + lg*8;
    bf16x8 a0 = *(const bf16x8*)(arow);
    bf16x8 a1 = *(const bf16x8*)(arow + 32);
    bf16x8 a2 = *(const bf16x8*)(arow + 64);
    #pragma unroll 4
    for (int nt = 0; nt < 24; nt++){
      const u16* wrow = W1b + (nt*16 + l15)*96 + lg*8;
      f32x4 acc = {0.f,0.f,0.f,0.f};
      acc = __builtin_amdgcn_mfma_f32_16x16x32_bf16(a0, *(const bf16x8*)(wrow),      acc, 0, 0, 0);
      acc = __builtin_amdgcn_mfma_f32_16x16x32_bf16(a1, *(const bf16x8*)(wrow + 32), acc, 0, 0, 0);
      acc = __builtin_amdgcn_mfma_f32_16x16x32_bf16(a2, *(const bf16x8*)(wrow + 64), acc, 0, 0, 0);
      int n = nt*16 + l15;
      float bias = b1[n];
      #pragma unroll
      for (int r = 0; r < 4; r++){
        float v = acc[r] + bias;
        float h = 0.5f*v*(1.f + erff(v*0.7071067811865475f));
        H[(wv*16 + lg*4 + r)*HS + n] = f2bf(h);
      }
    }
  }
  __syncthreads();

  {
    const u16* arow = H + myrow*HS + lg*8;
    bf16x8 ar[12];
    #pragma unroll
    for (int ks = 0; ks < 12; ks++) ar[ks] = *(const bf16x8*)(arow + ks*32);
    #pragma unroll
    for (int nt = 0; nt < 6; nt++){
      const u16* wrow = W2b + (nt*16 + l15)*384 + lg*8;
      f32x4 acc = {0.f,0.f,0.f,0.f};
      #pragma unroll
      for (int ks = 0; ks < 12; ks++)
        acc = __builtin_amdgcn_mfma_f32_16x16x32_bf16(ar[ks], *(const bf16x8*)(wrow + ks*32), acc, 0, 0, 0);
      int c = nt*16 + l15;
      float bias = bb2[c];
      #pragma unroll
      for (int r = 0; r < 4; r++){
        size_t tok = tb + wv*16 + lg*4 + r;
        out[tok*192 + 96 + c] = x[tok*192 + 96 + c] + acc[r] + bias;
      }
    }
  }
}

extern "C" void kernel_launch(void* const* d_in, const int* in_sizes, int n_in,
                              void* d_out, int out_size, void* d_ws, size_t ws_size,
                              hipStream_t stream){
  const float* x    = (const float*)d_in[0];
  const float* mask = (const float*)d_in[1];
  const int*   reli = (const int*)d_in[2];
  const float* n1g  = (const float*)d_in[3];
  const float* n1b  = (const float*)d_in[4];
  const float* qkvw = (const float*)d_in[5];
  const float* qkvb = (const float*)d_in[6];
  const float* btab = (const float*)d_in[7];
  const float* pw   = (const float*)d_in[8];
  const float* pb   = (const float*)d_in[9];
  const float* n2g  = (const float*)d_in[10];
  const float* n2b  = (const float*)d_in[11];
  const float* w1   = (const float*)d_in[12];
  const float* b1   = (const float*)d_in[13];
  const float* w2   = (const float*)d_in[14];
  const float* b2   = (const float*)d_in[15];
  float* out = (float*)d_out;

  u16* xn   = (u16*)d_ws;                          // 1024*98*96 bf16
  u16* attn = xn + (size_t)NWIN*98*96;
  u16* Wb   = attn + (size_t)NWIN*98*96;           // qkv 288*96
  u16* Pwb  = Wb + 288*96;                         // 96*96
  u16* W1b  = Pwb + 96*96;                         // 384*96
  u16* W2b  = W1b + 384*96;                        // 96*384
  float* bsc = (float*)(W2b + 96*384);             // 288 f32
  float* comb = bsc + 288;                         // 8*3*112*112 f32 = 1.2 MB

  k0_prep<<<432,   256, 0, stream>>>(qkvw, qkvb, pw, w1, w2, Wb, bsc);
  k0b_comb<<<1176, 256, 0, stream>>>(btab, reli, mask, comb);
  k1_ln  <<<25088, 256, 0, stream>>>(x, n1g, n1b, xn);
  k2_attn<<<3072,  256, 0, stream>>>(xn, Wb, bsc, comb, attn);
  k3_proj<<<1568,  256, 0, stream>>>(attn, Pwb, pb, x, out);
  k4_mlp <<<1568,  256, 0, stream>>>(out, n2g, n2b, W1b, b1, W2b, b2, x, out);
}

// Round 5
// 211.972 us; speedup vs baseline: 10.3560x; 1.1438x over previous
//
#include <hip/hip_runtime.h>
#include <math.h>

typedef unsigned int u32;
typedef unsigned short u16;

typedef __attribute__((ext_vector_type(8))) short bf16x8;
typedef __attribute__((ext_vector_type(4))) float f32x4;

#define NTOK 98
#define NWIN 1024

// LDS geometry for k2 (u16 units). Total 26640 u16 = 53280 B -> 3 blocks/CU.
#define XS_STR 104
#define QK_STR 40
#define P_STR  136
#define Q_BASE 13328
#define K_BASE 17808
#define VT_BASE 22288
#define LDS_U16 26640

__device__ __forceinline__ float bflo(u32 u){ union{u32 i; float f;} c; c.i = u<<16; return c.f; }
__device__ __forceinline__ float bfhi(u32 u){ union{u32 i; float f;} c; c.i = u & 0xffff0000u; return c.f; }
__device__ __forceinline__ u16 f2bf(float f){
  union{float f; u32 i;} c; c.f = f;
  u32 x = c.i;
  return (u16)((x + 0x7fffu + ((x>>16)&1u)) >> 16);
}

__device__ __forceinline__ int src_token(int win, int t){
  int b  = win >> 9;
  int wr = win & 511;
  int db = wr >> 6, hb = (wr >> 3) & 7, wb = wr & 7;
  int di = t / 49, r = t - di*49;
  int hi = r / 7,  wi = r - hi*7;
  int d = (db*2 + di + 1) & 15;
  int h = hb*7 + hi + 3; if (h >= 56) h -= 56;
  int w = wb*7 + wi + 3; if (w >= 56) w -= 56;
  return ((b*16 + d)*56 + h)*56 + w;
}

// ---------------- K0: preconvert all GEMM weights to bf16 ----------------
__global__ __launch_bounds__(256) void k0_prep(const float* __restrict__ qkvw,
    const float* __restrict__ qkvb, const float* __restrict__ pw,
    const float* __restrict__ w1, const float* __restrict__ w2,
    u16* __restrict__ Wb, float* __restrict__ bs){
  int i = blockIdx.x*256 + threadIdx.x;
  if (i < 288*96){
    float v = qkvw[i];
    if (i < 96*96) v *= 0.17677669529663687f;
    Wb[i] = f2bf(v);
  } else if (i < 288*96 + 96*96){
    Wb[i] = f2bf(pw[i - 288*96]);
  } else if (i < 288*96 + 96*96 + 384*96){
    Wb[i] = f2bf(w1[i - (288*96 + 96*96)]);
  } else if (i < 288*96 + 96*96 + 384*96 + 96*384){
    Wb[i] = f2bf(w2[i - (288*96 + 96*96 + 384*96)]);
  }
  if (i < 288){
    float v = qkvb[i];
    if (i < 96) v *= 0.17677669529663687f;
    bs[i] = v;
  }
}

// ---------------- K0b: comb[m][hd][112][112] = rel_bias + mask ----------------
__global__ __launch_bounds__(256) void k0b_comb(const float* __restrict__ bias_tab,
    const int* __restrict__ rel_idx, const float* __restrict__ mask,
    float* __restrict__ comb){
  int idx = blockIdx.x*256 + threadIdx.x;
  if (idx >= 8*3*112*112) return;
  int m  = idx / 37632; int r1 = idx - m*37632;
  int hd = r1 / 12544;  int r2 = r1 - hd*12544;
  int i  = r2 / 112,    j  = r2 - i*112;
  float v = -1e30f;
  if (i < 98 && j < 98){
    int wr = ((m>>2)&1)*448 + ((m>>1)&1)*56 + (m&1)*7;
    v = bias_tab[rel_idx[i*98+j]*3 + hd] + mask[(size_t)wr*9604 + i*98 + j];
  }
  comb[idx] = v;
}

// ---------------- K1: LN(x2) + shift + window partition -> xn (bf16) ----------------
__global__ __launch_bounds__(256) void k1_ln(const float* __restrict__ x,
      const float* __restrict__ g, const float* __restrict__ bb, u16* __restrict__ xn){
  int wid  = (blockIdx.x << 2) + (threadIdx.x >> 6);
  int lane = threadIdx.x & 63;
  if (wid >= NWIN*NTOK) return;
  int win = wid / NTOK, t = wid - win*NTOK;
  int tok = src_token(win, t);
  const float* xp = x + (size_t)tok*192 + 96;
  float a0 = 0.f, a1 = 0.f;
  if (lane < 48){ float2 v = *(const float2*)(xp + (lane<<1)); a0 = v.x; a1 = v.y; }
  float s = a0 + a1, s2 = a0*a0 + a1*a1;
  #pragma unroll
  for (int o = 32; o; o >>= 1){ s += __shfl_xor(s, o); s2 += __shfl_xor(s2, o); }
  float mean = s * (1.f/96.f);
  float rstd = rsqrtf(s2*(1.f/96.f) - mean*mean + 1e-5f);
  if (lane < 48){
    float r0 = (a0-mean)*rstd*g[2*lane]   + bb[2*lane];
    float r1 = (a1-mean)*rstd*g[2*lane+1] + bb[2*lane+1];
    u32 pk = (u32)f2bf(r0) | ((u32)f2bf(r1) << 16);
    *(u32*)(xn + (size_t)wid*96 + (lane<<1)) = pk;
  }
}

// ---------------- K2: per (window, head) MFMA attention ----------------
__global__ __launch_bounds__(256) void k2_attn(const u16* __restrict__ xn,
    const u16* __restrict__ Wb, const float* __restrict__ bs,
    const float* __restrict__ comb, u16* __restrict__ attn_o){
  __shared__ __align__(16) u16 lds[LDS_U16];
  int tid  = threadIdx.x;
  int lane = tid & 63, wv = tid >> 6;
  int l15  = lane & 15, lg = lane >> 4;
  int win = blockIdx.x / 3, hd = blockIdx.x - win*3;

  {
    const u32* xw = (const u32*)(xn + (size_t)win*98*96);
    u32* xs32 = (u32*)lds;
    for (int i = tid; i < 98*48; i += 256){
      int r = i/48, c = i - r*48;
      xs32[r*52 + c] = xw[i];
    }
    for (int i = tid; i < 14*52; i += 256){
      int r = 98 + i/52, c = i - (i/52)*52;
      xs32[r*52 + c] = 0;
    }
    u32* vt32 = (u32*)(lds + VT_BASE);
    for (int i = tid; i < 32*12; i += 256){
      int d = i/12, c = i - d*12;
      vt32[d*68 + 56 + c] = 0;
    }
  }
  __syncthreads();

  for (int t = wv; t < 42; t += 4){
    f32x4 acc = {0.f,0.f,0.f,0.f};
    if (t < 28){
      int tt = (t < 14) ? t : t - 14;
      int mt = tt >> 1, nt = tt & 1;
      int ch = hd*32 + nt*16 + l15 + ((t < 14) ? 0 : 96);
      const u16* wrow = Wb + ch*96 + lg*8;
      const u16* xsrow = lds + (mt*16 + l15)*XS_STR;
      #pragma unroll
      for (int ks = 0; ks < 3; ks++){
        bf16x8 a = *(const bf16x8*)(xsrow + ks*32 + lg*8);
        bf16x8 b = *(const bf16x8*)(wrow + ks*32);
        acc = __builtin_amdgcn_mfma_f32_16x16x32_bf16(a, b, acc, 0, 0, 0);
      }
      float bias = bs[ch];
      u16* dst = lds + ((t < 14) ? Q_BASE : K_BASE);
      int col = nt*16 + l15;
      int rbase = mt*16 + lg*4;
      #pragma unroll
      for (int r = 0; r < 4; r++)
        dst[(rbase+r)*QK_STR + col] = f2bf(acc[r] + bias);
    } else {
      int tt = t - 28; int mt = tt/7, nt = tt - mt*7;
      int ch = 192 + hd*32 + mt*16 + l15;
      const u16* wrow = Wb + ch*96 + lg*8;
      const u16* xsrow = lds + (nt*16 + l15)*XS_STR;
      #pragma unroll
      for (int ks = 0; ks < 3; ks++){
        bf16x8 a = *(const bf16x8*)(wrow + ks*32);
        bf16x8 b = *(const bf16x8*)(xsrow + ks*32 + lg*8);
        acc = __builtin_amdgcn_mfma_f32_16x16x32_bf16(a, b, acc, 0, 0, 0);
      }
      int dbase = mt*16 + lg*4;
      #pragma unroll
      for (int r = 0; r < 4; r++){
        float bias = bs[192 + hd*32 + dbase + r];
        lds[VT_BASE + (dbase+r)*P_STR + nt*16 + l15] = f2bf(acc[r] + bias);
      }
    }
  }
  __syncthreads();

  {
    int wr = win & 511;
    int maskid = ((wr>>6)==7)*4 + (((wr>>3)&7)==7)*2 + ((wr&7)==7);
    const float* cb_base = comb + (size_t)(maskid*3 + hd)*12544 + l15;

    for (int mt = wv; mt < 7; mt += 4){
      {
        u32* p32 = (u32*)lds;
        int rmax = (mt == 6) ? 2 : 16;
        for (int i = lane; i < rmax*12; i += 64){
          int rr = i/12, c = i - rr*12;
          p32[(mt*16+rr)*68 + 56 + c] = 0;
        }
      }
      int ibase = mt*16 + lg*4;
      float cb[4][7];
      #pragma unroll
      for (int r = 0; r < 4; r++){
        const float* cbp = cb_base + (ibase + r)*112;
        #pragma unroll
        for (int nt = 0; nt < 7; nt++) cb[r][nt] = cbp[nt*16];
      }
      const u16* qrow = lds + Q_BASE + (mt*16 + l15)*QK_STR;
      bf16x8 a = *(const bf16x8*)(qrow + lg*8);
      f32x4 s[7];
      #pragma unroll
      for (int nt = 0; nt < 7; nt++){
        const u16* krow = lds + K_BASE + (nt*16 + l15)*QK_STR;
        bf16x8 b = *(const bf16x8*)(krow + lg*8);
        f32x4 z = {0.f,0.f,0.f,0.f};
        s[nt] = __builtin_amdgcn_mfma_f32_16x16x32_bf16(a, b, z, 0, 0, 0);
      }
      #pragma unroll
      for (int r = 0; r < 4; r++){
        int i = ibase + r;
        float sv[7];
        float mx = -3.0e38f;
        #pragma unroll
        for (int nt = 0; nt < 7; nt++){
          float v = s[nt][r] + cb[r][nt];
          sv[nt] = v; mx = fmaxf(mx, v);
        }
        #pragma unroll
        for (int off = 1; off < 16; off <<= 1) mx = fmaxf(mx, __shfl_xor(mx, off));
        float sum = 0.f;
        #pragma unroll
        for (int nt = 0; nt < 7; nt++){
          float e = __expf(sv[nt] - mx);
          sv[nt] = e; sum += e;
        }
        #pragma unroll
        for (int off = 1; off < 16; off <<= 1) sum += __shfl_xor(sum, off);
        float inv = 1.f / sum;
        if (i < 98){
          #pragma unroll
          for (int nt = 0; nt < 7; nt++)
            lds[i*P_STR + nt*16 + l15] = f2bf(sv[nt]*inv);
        }
      }
    }
  }
  __syncthreads();

  for (int t = wv; t < 14; t += 4){
    int mt = t >> 1, nt = t & 1;
    const u16* prow = lds + (mt*16 + l15)*P_STR;
    const u16* vrow = lds + VT_BASE + (nt*16 + l15)*P_STR;
    f32x4 acc = {0.f,0.f,0.f,0.f};
    #pragma unroll
    for (int ks = 0; ks < 4; ks++){
      bf16x8 a = *(const bf16x8*)(prow + ks*32 + lg*8);
      bf16x8 b = *(const bf16x8*)(vrow + ks*32 + lg*8);
      acc = __builtin_amdgcn_mfma_f32_16x16x32_bf16(a, b, acc, 0, 0, 0);
    }
    int ibase = mt*16 + lg*4;
    int d = nt*16 + l15;
    #pragma unroll
    for (int r = 0; r < 4; r++){
      int i = ibase + r;
      if (i < 98) attn_o[((size_t)win*98 + i)*96 + hd*32 + d] = f2bf(acc[r]);
    }
  }
}

// ---------------- K3: MFMA proj + x1 add -> y1 (out[...,0:96]) ----------------
__global__ __launch_bounds__(256) void k3_proj(const u16* __restrict__ attn_o,
    const u16* __restrict__ Pwb, const float* __restrict__ pb,
    const float* __restrict__ x, float* __restrict__ out){
  __shared__ __align__(16) u16 aw[64*104];
  int tid = threadIdx.x;
  int lane = tid & 63, wv = tid >> 6;
  int l15 = lane & 15, lg = lane >> 4;
  size_t base = (size_t)blockIdx.x * 64;

  const u32* src = (const u32*)(attn_o + base*96);
  u32* aw32 = (u32*)aw;
  for (int i = tid; i < 64*48; i += 256){
    int r = i/48, c = i - r*48;
    aw32[r*52 + c] = src[i];
  }
  __syncthreads();

  const u16* arow = aw + (wv*16 + l15)*104 + lg*8;
  bf16x8 a0 = *(const bf16x8*)(arow);
  bf16x8 a1 = *(const bf16x8*)(arow + 32);
  bf16x8 a2 = *(const bf16x8*)(arow + 64);

  #pragma unroll
  for (int nt = 0; nt < 6; nt++){
    const u16* wrow = Pwb + (nt*16 + l15)*96 + lg*8;
    f32x4 acc = {0.f,0.f,0.f,0.f};
    acc = __builtin_amdgcn_mfma_f32_16x16x32_bf16(a0, *(const bf16x8*)(wrow),      acc, 0, 0, 0);
    acc = __builtin_amdgcn_mfma_f32_16x16x32_bf16(a1, *(const bf16x8*)(wrow + 32), acc, 0, 0, 0);
    acc = __builtin_amdgcn_mfma_f32_16x16x32_bf16(a2, *(const bf16x8*)(wrow + 64), acc, 0, 0, 0);
    int n = nt*16 + l15;
    float bias = pb[n];
    #pragma unroll
    for (int r = 0; r < 4; r++){
      int wt = (int)base + wv*16 + lg*4 + r;
      int win = wt / 98, t = wt - win*98;
      int tok = src_token(win, t);
      out[(size_t)tok*192 + n] = x[(size_t)tok*192 + n] + acc[r] + bias;
    }
  }
}

// ---------------- K4: MFMA MLP, 32 tokens/block for occupancy ----------------
#define HS 392
__global__ __launch_bounds__(256, 5) void k4_mlp(const float* __restrict__ y1,
    const float* __restrict__ g2, const float* __restrict__ b2,
    const u16* __restrict__ W1b, const float* __restrict__ b1,
    const u16* __restrict__ W2b, const float* __restrict__ bb2,
    const float* __restrict__ x, float* __restrict__ out){
  __shared__ __align__(16) u16 yn[32*104];   // 6656 B
  __shared__ __align__(16) u16 H[32*HS];     // 25088 B
  int tid = threadIdx.x;
  int lane = tid & 63, wv = tid >> 6;
  int l15 = lane & 15, lg = lane >> 4;
  size_t tb = (size_t)blockIdx.x * 32;

  // ---- A: LN -> yn (bf16). 8 threads per token, 12 f32 each.
  {
    int tk = tid >> 3, c8 = tid & 7;
    const float4* yp = (const float4*)(y1 + (tb + tk)*192 + c8*12);
    float4 v4[3];
    #pragma unroll
    for (int j = 0; j < 3; j++) v4[j] = yp[j];
    float s = 0.f, s2 = 0.f;
    #pragma unroll
    for (int j = 0; j < 3; j++){
      s  += v4[j].x + v4[j].y + v4[j].z + v4[j].w;
      s2 += v4[j].x*v4[j].x + v4[j].y*v4[j].y + v4[j].z*v4[j].z + v4[j].w*v4[j].w;
    }
    s  += __shfl_xor(s, 1);  s  += __shfl_xor(s, 2);  s  += __shfl_xor(s, 4);
    s2 += __shfl_xor(s2, 1); s2 += __shfl_xor(s2, 2); s2 += __shfl_xor(s2, 4);
    float mean = s * (1.f/96.f);
    float rstd = rsqrtf(s2*(1.f/96.f) - mean*mean + 1e-5f);
    u32* dst = (u32*)(yn + tk*104) + c8*6;
    const float* gp = g2 + c8*12;
    const float* bp = b2 + c8*12;
    #pragma unroll
    for (int p = 0; p < 6; p++){
      float e0 = (p & 1) ? v4[p>>1].z : v4[p>>1].x;
      float e1 = (p & 1) ? v4[p>>1].w : v4[p>>1].y;
      float r0 = (e0 - mean)*rstd*gp[2*p]   + bp[2*p];
      float r1 = (e1 - mean)*rstd*gp[2*p+1] + bp[2*p+1];
      dst[p] = (u32)f2bf(r0) | ((u32)f2bf(r1) << 16);
    }
  }
  __syncthreads();

  int mt = wv & 1;            // wave's m-tile (16 tokens)
  // ---- B: fc1 + GELU -> H. wave covers nt in [ (wv>>1)*12, +12 ).
  {
    int ng = wv >> 1;
    const u16* arow = yn + (mt*16 + l15)*104 + lg*8;
    bf16x8 a0 = *(const bf16x8*)(arow);
    bf16x8 a1 = *(const bf16x8*)(arow + 32);
    bf16x8 a2 = *(const bf16x8*)(arow + 64);
    #pragma unroll 4
    for (int q = 0; q < 12; q++){
      int nt = ng*12 + q;
      const u16* wrow = W1b + (nt*16 + l15)*96 + lg*8;
      f32x4 acc = {0.f,0.f,0.f,0.f};
      acc = __builtin_amdgcn_mfma_f32_16x16x32_bf16(a0, *(const bf16x8*)(wrow),      acc, 0, 0, 0);
      acc = __builtin_amdgcn_mfma_f32_16x16x32_bf16(a1, *(const bf16x8*)(wrow + 32), acc, 0, 0, 0);
      acc = __builtin_amdgcn_mfma_f32_16x16x32_bf16(a2, *(const bf16x8*)(wrow + 64), acc, 0, 0, 0);
      int n = nt*16 + l15;
      float bias = b1[n];
      #pragma unroll
      for (int r = 0; r < 4; r++){
        float v = acc[r] + bias;
        float h = 0.5f*v*(1.f + erff(v*0.7071067811865475f));
        H[(mt*16 + lg*4 + r)*HS + n] = f2bf(h);
      }
    }
  }
  __syncthreads();

  // ---- C: fc2 + bias + residual. wave covers ct in [ (wv>>1)*3, +3 ), K=384.
  {
    int cg = wv >> 1;
    const u16* arow = H + (mt*16 + l15)*HS + lg*8;
    bf16x8 ar[12];
    #pragma unroll
    for (int ks = 0; ks < 12; ks++) ar[ks] = *(const bf16x8*)(arow + ks*32);
    #pragma unroll
    for (int q = 0; q < 3; q++){
      int ct = cg*3 + q;
      const u16* wrow = W2b + (ct*16 + l15)*384 + lg*8;
      f32x4 acc = {0.f,0.f,0.f,0.f};
      #pragma unroll
      for (int ks = 0; ks < 12; ks++)
        acc = __builtin_amdgcn_mfma_f32_16x16x32_bf16(ar[ks], *(const bf16x8*)(wrow + ks*32), acc, 0, 0, 0);
      int c = ct*16 + l15;
      float bias = bb2[c];
      #pragma unroll
      for (int r = 0; r < 4; r++){
        size_t tok = tb + mt*16 + lg*4 + r;
        out[tok*192 + 96 + c] = x[tok*192 + 96 + c] + acc[r] + bias;
      }
    }
  }
}

extern "C" void kernel_launch(void* const* d_in, const int* in_sizes, int n_in,
                              void* d_out, int out_size, void* d_ws, size_t ws_size,
                              hipStream_t stream){
  const float* x    = (const float*)d_in[0];
  const float* mask = (const float*)d_in[1];
  const int*   reli = (const int*)d_in[2];
  const float* n1g  = (const float*)d_in[3];
  const float* n1b  = (const float*)d_in[4];
  const float* qkvw = (const float*)d_in[5];
  const float* qkvb = (const float*)d_in[6];
  const float* btab = (const float*)d_in[7];
  const float* pw   = (const float*)d_in[8];
  const float* pb   = (const float*)d_in[9];
  const float* n2g  = (const float*)d_in[10];
  const float* n2b  = (const float*)d_in[11];
  const float* w1   = (const float*)d_in[12];
  const float* b1   = (const float*)d_in[13];
  const float* w2   = (const float*)d_in[14];
  const float* b2   = (const float*)d_in[15];
  float* out = (float*)d_out;

  u16* xn   = (u16*)d_ws;                          // 1024*98*96 bf16
  u16* attn = xn + (size_t)NWIN*98*96;
  u16* Wb   = attn + (size_t)NWIN*98*96;           // qkv 288*96
  u16* Pwb  = Wb + 288*96;                         // 96*96
  u16* W1b  = Pwb + 96*96;                         // 384*96
  u16* W2b  = W1b + 384*96;                        // 96*384
  float* bsc = (float*)(W2b + 96*384);             // 288 f32
  float* comb = bsc + 288;                         // 8*3*112*112 f32

  k0_prep<<<432,   256, 0, stream>>>(qkvw, qkvb, pw, w1, w2, Wb, bsc);
  k0b_comb<<<1176, 256, 0, stream>>>(btab, reli, mask, comb);
  k1_ln  <<<25088, 256, 0, stream>>>(x, n1g, n1b, xn);
  k2_attn<<<3072,  256, 0, stream>>>(xn, Wb, bsc, comb, attn);
  k3_proj<<<1568,  256, 0, stream>>>(attn, Pwb, pb, x, out);
  k4_mlp <<<3136,  256, 0, stream>>>(out, n2g, n2b, W1b, b1, W2b, b2, x, out);
}

// Round 6
// 193.574 us; speedup vs baseline: 11.3403x; 1.0950x over previous
//
#include <hip/hip_runtime.h>
#include <math.h>

typedef unsigned int u32;
typedef unsigned short u16;

typedef __attribute__((ext_vector_type(8))) short bf16x8;
typedef __attribute__((ext_vector_type(4))) float f32x4;

#define NTOK 98
#define NWIN 1024

// LDS geometry for k2 (u16 units). Total 26640 u16 = 53280 B -> 3 blocks/CU.
#define XS_STR 104
#define QK_STR 40
#define P_STR  136
#define Q_BASE 13328
#define K_BASE 17808
#define VT_BASE 22288
#define LDS_U16 26640

__device__ __forceinline__ float bflo(u32 u){ union{u32 i; float f;} c; c.i = u<<16; return c.f; }
__device__ __forceinline__ float bfhi(u32 u){ union{u32 i; float f;} c; c.i = u & 0xffff0000u; return c.f; }
__device__ __forceinline__ u16 f2bf(float f){
  union{float f; u32 i;} c; c.f = f;
  u32 x = c.i;
  return (u16)((x + 0x7fffu + ((x>>16)&1u)) >> 16);
}

// GELU with A&S 7.1.26 erf (abs err 1.5e-7)
__device__ __forceinline__ float gelu_f(float v){
  float z  = v * 0.70710678118654752f;
  float az = fabsf(z);
  float t  = __builtin_amdgcn_rcpf(1.f + 0.3275911f*az);
  float p  = ((((1.061405429f*t - 1.453152027f)*t + 1.421413741f)*t
               - 0.284496736f)*t + 0.254829592f)*t;
  float er = 1.f - p*__expf(-z*z);
  er = copysignf(er, z);
  return 0.5f*v*(1.f + er);
}

__device__ __forceinline__ int src_token(int win, int t){
  int b  = win >> 9;
  int wr = win & 511;
  int db = wr >> 6, hb = (wr >> 3) & 7, wb = wr & 7;
  int di = t / 49, r = t - di*49;
  int hi = r / 7,  wi = r - hi*7;
  int d = (db*2 + di + 1) & 15;
  int h = hb*7 + hi + 3; if (h >= 56) h -= 56;
  int w = wb*7 + wi + 3; if (w >= 56) w -= 56;
  return ((b*16 + d)*56 + h)*56 + w;
}

// ---------------- K0: preconvert all GEMM weights to bf16 ----------------
__global__ __launch_bounds__(256) void k0_prep(const float* __restrict__ qkvw,
    const float* __restrict__ qkvb, const float* __restrict__ pw,
    const float* __restrict__ w1, const float* __restrict__ w2,
    u16* __restrict__ Wb, float* __restrict__ bs){
  int i = blockIdx.x*256 + threadIdx.x;
  if (i < 288*96){
    float v = qkvw[i];
    if (i < 96*96) v *= 0.17677669529663687f;
    Wb[i] = f2bf(v);
  } else if (i < 288*96 + 96*96){
    Wb[i] = f2bf(pw[i - 288*96]);
  } else if (i < 288*96 + 96*96 + 384*96){
    Wb[i] = f2bf(w1[i - (288*96 + 96*96)]);
  } else if (i < 288*96 + 96*96 + 384*96 + 96*384){
    Wb[i] = f2bf(w2[i - (288*96 + 96*96 + 384*96)]);
  }
  if (i < 288){
    float v = qkvb[i];
    if (i < 96) v *= 0.17677669529663687f;
    bs[i] = v;
  }
}

// ---------------- K0b: comb[m][hd][112][112] = rel_bias + mask ----------------
__global__ __launch_bounds__(256) void k0b_comb(const float* __restrict__ bias_tab,
    const int* __restrict__ rel_idx, const float* __restrict__ mask,
    float* __restrict__ comb){
  int idx = blockIdx.x*256 + threadIdx.x;
  if (idx >= 8*3*112*112) return;
  int m  = idx / 37632; int r1 = idx - m*37632;
  int hd = r1 / 12544;  int r2 = r1 - hd*12544;
  int i  = r2 / 112,    j  = r2 - i*112;
  float v = -1e30f;
  if (i < 98 && j < 98){
    int wr = ((m>>2)&1)*448 + ((m>>1)&1)*56 + (m&1)*7;
    v = bias_tab[rel_idx[i*98+j]*3 + hd] + mask[(size_t)wr*9604 + i*98 + j];
  }
  comb[idx] = v;
}

// ---------------- K1: LN(x2) + shift + window partition -> xn (bf16) ----------------
__global__ __launch_bounds__(256) void k1_ln(const float* __restrict__ x,
      const float* __restrict__ g, const float* __restrict__ bb, u16* __restrict__ xn){
  int wid  = (blockIdx.x << 2) + (threadIdx.x >> 6);
  int lane = threadIdx.x & 63;
  if (wid >= NWIN*NTOK) return;
  int win = wid / NTOK, t = wid - win*NTOK;
  int tok = src_token(win, t);
  const float* xp = x + (size_t)tok*192 + 96;
  float a0 = 0.f, a1 = 0.f;
  if (lane < 48){ float2 v = *(const float2*)(xp + (lane<<1)); a0 = v.x; a1 = v.y; }
  float s = a0 + a1, s2 = a0*a0 + a1*a1;
  #pragma unroll
  for (int o = 32; o; o >>= 1){ s += __shfl_xor(s, o); s2 += __shfl_xor(s2, o); }
  float mean = s * (1.f/96.f);
  float rstd = rsqrtf(s2*(1.f/96.f) - mean*mean + 1e-5f);
  if (lane < 48){
    float r0 = (a0-mean)*rstd*g[2*lane]   + bb[2*lane];
    float r1 = (a1-mean)*rstd*g[2*lane+1] + bb[2*lane+1];
    u32 pk = (u32)f2bf(r0) | ((u32)f2bf(r1) << 16);
    *(u32*)(xn + (size_t)wid*96 + (lane<<1)) = pk;
  }
}

// ---------------- K2: per (window, head) MFMA attention ----------------
__global__ __launch_bounds__(256) void k2_attn(const u16* __restrict__ xn,
    const u16* __restrict__ Wb, const float* __restrict__ bs,
    const float* __restrict__ comb, u16* __restrict__ attn_o){
  __shared__ __align__(16) u16 lds[LDS_U16];
  int tid  = threadIdx.x;
  int lane = tid & 63, wv = tid >> 6;
  int l15  = lane & 15, lg = lane >> 4;
  int win = blockIdx.x / 3, hd = blockIdx.x - win*3;

  {
    const u32* xw = (const u32*)(xn + (size_t)win*98*96);
    u32* xs32 = (u32*)lds;
    for (int i = tid; i < 98*48; i += 256){
      int r = i/48, c = i - r*48;
      xs32[r*52 + c] = xw[i];
    }
    for (int i = tid; i < 14*52; i += 256){
      int r = 98 + i/52, c = i - (i/52)*52;
      xs32[r*52 + c] = 0;
    }
    u32* vt32 = (u32*)(lds + VT_BASE);
    for (int i = tid; i < 32*12; i += 256){
      int d = i/12, c = i - d*12;
      vt32[d*68 + 56 + c] = 0;
    }
  }
  __syncthreads();

  for (int t = wv; t < 42; t += 4){
    f32x4 acc = {0.f,0.f,0.f,0.f};
    if (t < 28){
      int tt = (t < 14) ? t : t - 14;
      int mt = tt >> 1, nt = tt & 1;
      int ch = hd*32 + nt*16 + l15 + ((t < 14) ? 0 : 96);
      const u16* wrow = Wb + ch*96 + lg*8;
      const u16* xsrow = lds + (mt*16 + l15)*XS_STR;
      #pragma unroll
      for (int ks = 0; ks < 3; ks++){
        bf16x8 a = *(const bf16x8*)(xsrow + ks*32 + lg*8);
        bf16x8 b = *(const bf16x8*)(wrow + ks*32);
        acc = __builtin_amdgcn_mfma_f32_16x16x32_bf16(a, b, acc, 0, 0, 0);
      }
      float bias = bs[ch];
      u16* dst = lds + ((t < 14) ? Q_BASE : K_BASE);
      int col = nt*16 + l15;
      int rbase = mt*16 + lg*4;
      #pragma unroll
      for (int r = 0; r < 4; r++)
        dst[(rbase+r)*QK_STR + col] = f2bf(acc[r] + bias);
    } else {
      int tt = t - 28; int mt = tt/7, nt = tt - mt*7;
      int ch = 192 + hd*32 + mt*16 + l15;
      const u16* wrow = Wb + ch*96 + lg*8;
      const u16* xsrow = lds + (nt*16 + l15)*XS_STR;
      #pragma unroll
      for (int ks = 0; ks < 3; ks++){
        bf16x8 a = *(const bf16x8*)(wrow + ks*32);
        bf16x8 b = *(const bf16x8*)(xsrow + ks*32 + lg*8);
        acc = __builtin_amdgcn_mfma_f32_16x16x32_bf16(a, b, acc, 0, 0, 0);
      }
      int dbase = mt*16 + lg*4;
      #pragma unroll
      for (int r = 0; r < 4; r++){
        float bias = bs[192 + hd*32 + dbase + r];
        lds[VT_BASE + (dbase+r)*P_STR + nt*16 + l15] = f2bf(acc[r] + bias);
      }
    }
  }
  __syncthreads();

  {
    int wr = win & 511;
    int maskid = ((wr>>6)==7)*4 + (((wr>>3)&7)==7)*2 + ((wr&7)==7);
    const float* cb_base = comb + (size_t)(maskid*3 + hd)*12544 + l15;

    for (int mt = wv; mt < 7; mt += 4){
      {
        u32* p32 = (u32*)lds;
        int rmax = (mt == 6) ? 2 : 16;
        for (int i = lane; i < rmax*12; i += 64){
          int rr = i/12, c = i - rr*12;
          p32[(mt*16+rr)*68 + 56 + c] = 0;
        }
      }
      int ibase = mt*16 + lg*4;
      float cb[4][7];
      #pragma unroll
      for (int r = 0; r < 4; r++){
        const float* cbp = cb_base + (ibase + r)*112;
        #pragma unroll
        for (int nt = 0; nt < 7; nt++) cb[r][nt] = cbp[nt*16];
      }
      const u16* qrow = lds + Q_BASE + (mt*16 + l15)*QK_STR;
      bf16x8 a = *(const bf16x8*)(qrow + lg*8);
      f32x4 s[7];
      #pragma unroll
      for (int nt = 0; nt < 7; nt++){
        const u16* krow = lds + K_BASE + (nt*16 + l15)*QK_STR;
        bf16x8 b = *(const bf16x8*)(krow + lg*8);
        f32x4 z = {0.f,0.f,0.f,0.f};
        s[nt] = __builtin_amdgcn_mfma_f32_16x16x32_bf16(a, b, z, 0, 0, 0);
      }
      #pragma unroll
      for (int r = 0; r < 4; r++){
        int i = ibase + r;
        float sv[7];
        float mx = -3.0e38f;
        #pragma unroll
        for (int nt = 0; nt < 7; nt++){
          float v = s[nt][r] + cb[r][nt];
          sv[nt] = v; mx = fmaxf(mx, v);
        }
        #pragma unroll
        for (int off = 1; off < 16; off <<= 1) mx = fmaxf(mx, __shfl_xor(mx, off));
        float sum = 0.f;
        #pragma unroll
        for (int nt = 0; nt < 7; nt++){
          float e = __expf(sv[nt] - mx);
          sv[nt] = e; sum += e;
        }
        #pragma unroll
        for (int off = 1; off < 16; off <<= 1) sum += __shfl_xor(sum, off);
        float inv = 1.f / sum;
        if (i < 98){
          #pragma unroll
          for (int nt = 0; nt < 7; nt++)
            lds[i*P_STR + nt*16 + l15] = f2bf(sv[nt]*inv);
        }
      }
    }
  }
  __syncthreads();

  for (int t = wv; t < 14; t += 4){
    int mt = t >> 1, nt = t & 1;
    const u16* prow = lds + (mt*16 + l15)*P_STR;
    const u16* vrow = lds + VT_BASE + (nt*16 + l15)*P_STR;
    f32x4 acc = {0.f,0.f,0.f,0.f};
    #pragma unroll
    for (int ks = 0; ks < 4; ks++){
      bf16x8 a = *(const bf16x8*)(prow + ks*32 + lg*8);
      bf16x8 b = *(const bf16x8*)(vrow + ks*32 + lg*8);
      acc = __builtin_amdgcn_mfma_f32_16x16x32_bf16(a, b, acc, 0, 0, 0);
    }
    int ibase = mt*16 + lg*4;
    int d = nt*16 + l15;
    #pragma unroll
    for (int r = 0; r < 4; r++){
      int i = ibase + r;
      if (i < 98) attn_o[((size_t)win*98 + i)*96 + hd*32 + d] = f2bf(acc[r]);
    }
  }
}

// ---------------- K34: fused proj + x1 + LN + fc1 + GELU + fc2 + x2 ----------------
// 32 windowed tokens/block. LDS: H[0:12544] (aw[0:3328], y1f f32 @u16 3328..9728
// overlaid by lifetime), yn @12544..15872.  Total 31744 B.
#define HS 392
#define Y1F_U16 3328
#define YN_U16 12544
__global__ __launch_bounds__(256, 4) void k34_projmlp(const u16* __restrict__ attn_o,
    const u16* __restrict__ Pwb, const float* __restrict__ pb,
    const float* __restrict__ g2, const float* __restrict__ b2,
    const u16* __restrict__ W1b, const float* __restrict__ b1,
    const u16* __restrict__ W2b, const float* __restrict__ bb2,
    const float* __restrict__ x, float* __restrict__ out){
  __shared__ __align__(16) u16 lds[15872];
  int tid = threadIdx.x;
  int lane = tid & 63, wv = tid >> 6;
  int l15 = lane & 15, lg = lane >> 4;
  size_t base = (size_t)blockIdx.x * 32;
  int mt = wv & 1, ng = wv >> 1;
  float* y1f = (float*)(lds + Y1F_U16);

  // tokens this lane owns (rows mt*16+lg*4+r) in both proj and fc2
  int tok_r[4];
  {
    int wt0 = (int)base + mt*16 + lg*4;
    #pragma unroll
    for (int r = 0; r < 4; r++){
      int wt = wt0 + r; int win = wt/98;
      tok_r[r] = src_token(win, wt - win*98);
    }
  }

  // ---- stage aw (32x96 bf16, stride 104) ----
  {
    const u32* src = (const u32*)(attn_o + base*96);
    u32* aw32 = (u32*)lds;
    #pragma unroll
    for (int k = 0; k < 6; k++){
      int i = tid + k*256;
      int r = i/48, c = i - r*48;
      aw32[r*52 + c] = src[i];
    }
  }
  __syncthreads();

  // ---- proj + x1 residual -> out[...,0:96] and y1f ----
  {
    const u16* arow = lds + (mt*16 + l15)*104 + lg*8;
    bf16x8 a0 = *(const bf16x8*)(arow);
    bf16x8 a1 = *(const bf16x8*)(arow + 32);
    bf16x8 a2 = *(const bf16x8*)(arow + 64);
    #pragma unroll
    for (int q = 0; q < 3; q++){
      int nt = ng*3 + q;
      const u16* wrow = Pwb + (nt*16 + l15)*96 + lg*8;
      f32x4 acc = {0.f,0.f,0.f,0.f};
      acc = __builtin_amdgcn_mfma_f32_16x16x32_bf16(a0, *(const bf16x8*)(wrow),      acc, 0, 0, 0);
      acc = __builtin_amdgcn_mfma_f32_16x16x32_bf16(a1, *(const bf16x8*)(wrow + 32), acc, 0, 0, 0);
      acc = __builtin_amdgcn_mfma_f32_16x16x32_bf16(a2, *(const bf16x8*)(wrow + 64), acc, 0, 0, 0);
      int n = nt*16 + l15;
      float bias = pb[n];
      #pragma unroll
      for (int r = 0; r < 4; r++){
        float y = acc[r] + bias + x[(size_t)tok_r[r]*192 + n];
        out[(size_t)tok_r[r]*192 + n] = y;
        y1f[(mt*16 + lg*4 + r)*100 + n] = y;
      }
    }
  }
  __syncthreads();

  // ---- LN(y1) -> yn (bf16). 8 threads/token. ----
  {
    int tk = tid >> 3, c8 = tid & 7;
    const float4* yp = (const float4*)(y1f + tk*100 + c8*12);
    float4 v4[3];
    #pragma unroll
    for (int j = 0; j < 3; j++) v4[j] = yp[j];
    float s = 0.f, s2 = 0.f;
    #pragma unroll
    for (int j = 0; j < 3; j++){
      s  += v4[j].x + v4[j].y + v4[j].z + v4[j].w;
      s2 += v4[j].x*v4[j].x + v4[j].y*v4[j].y + v4[j].z*v4[j].z + v4[j].w*v4[j].w;
    }
    s  += __shfl_xor(s, 1);  s  += __shfl_xor(s, 2);  s  += __shfl_xor(s, 4);
    s2 += __shfl_xor(s2, 1); s2 += __shfl_xor(s2, 2); s2 += __shfl_xor(s2, 4);
    float mean = s * (1.f/96.f);
    float rstd = rsqrtf(s2*(1.f/96.f) - mean*mean + 1e-5f);
    u32* dst = (u32*)(lds + YN_U16) + tk*52 + c8*6;
    const float* gp = g2 + c8*12;
    const float* bp = b2 + c8*12;
    #pragma unroll
    for (int p = 0; p < 6; p++){
      float e0 = (p & 1) ? v4[p>>1].z : v4[p>>1].x;
      float e1 = (p & 1) ? v4[p>>1].w : v4[p>>1].y;
      float r0 = (e0 - mean)*rstd*gp[2*p]   + bp[2*p];
      float r1 = (e1 - mean)*rstd*gp[2*p+1] + bp[2*p+1];
      dst[p] = (u32)f2bf(r0) | ((u32)f2bf(r1) << 16);
    }
  }
  __syncthreads();

  // ---- fc1 + GELU -> H (overlays aw/y1f). 1-deep weight prefetch. ----
  {
    const u16* arow = lds + YN_U16 + (mt*16 + l15)*104 + lg*8;
    bf16x8 a0 = *(const bf16x8*)(arow);
    bf16x8 a1 = *(const bf16x8*)(arow + 32);
    bf16x8 a2 = *(const bf16x8*)(arow + 64);
    const u16* wrow = W1b + ((ng*12)*16 + l15)*96 + lg*8;
    bf16x8 w0 = *(const bf16x8*)(wrow);
    bf16x8 w1 = *(const bf16x8*)(wrow + 32);
    bf16x8 w2 = *(const bf16x8*)(wrow + 64);
    #pragma unroll
    for (int q = 0; q < 12; q++){
      bf16x8 p0 = w0, p1 = w1, p2 = w2;
      if (q < 11){
        const u16* nw = wrow + (q+1)*1536;
        w0 = *(const bf16x8*)(nw);
        w1 = *(const bf16x8*)(nw + 32);
        w2 = *(const bf16x8*)(nw + 64);
      }
      f32x4 acc = {0.f,0.f,0.f,0.f};
      acc = __builtin_amdgcn_mfma_f32_16x16x32_bf16(a0, p0, acc, 0, 0, 0);
      acc = __builtin_amdgcn_mfma_f32_16x16x32_bf16(a1, p1, acc, 0, 0, 0);
      acc = __builtin_amdgcn_mfma_f32_16x16x32_bf16(a2, p2, acc, 0, 0, 0);
      int n = (ng*12 + q)*16 + l15;
      float bias = b1[n];
      #pragma unroll
      for (int r = 0; r < 4; r++)
        lds[(mt*16 + lg*4 + r)*HS + n] = f2bf(gelu_f(acc[r] + bias));
    }
  }
  __syncthreads();

  // ---- fc2 + bias + x2 residual -> out[...,96:192]. ----
  {
    const u16* arow = lds + (mt*16 + l15)*HS + lg*8;
    bf16x8 ar[12];
    #pragma unroll
    for (int ks = 0; ks < 12; ks++) ar[ks] = *(const bf16x8*)(arow + ks*32);
    #pragma unroll
    for (int q = 0; q < 3; q++){
      int ct = ng*3 + q;
      const u16* wrow = W2b + (ct*16 + l15)*384 + lg*8;
      bf16x8 wr[12];
      #pragma unroll
      for (int ks = 0; ks < 12; ks++) wr[ks] = *(const bf16x8*)(wrow + ks*32);
      f32x4 acc = {0.f,0.f,0.f,0.f};
      #pragma unroll
      for (int ks = 0; ks < 12; ks++)
        acc = __builtin_amdgcn_mfma_f32_16x16x32_bf16(ar[ks], wr[ks], acc, 0, 0, 0);
      int c = ct*16 + l15;
      float bias = bb2[c];
      #pragma unroll
      for (int r = 0; r < 4; r++){
        size_t o = (size_t)tok_r[r]*192 + 96 + c;
        out[o] = x[o] + acc[r] + bias;
      }
    }
  }
}

extern "C" void kernel_launch(void* const* d_in, const int* in_sizes, int n_in,
                              void* d_out, int out_size, void* d_ws, size_t ws_size,
                              hipStream_t stream){
  const float* x    = (const float*)d_in[0];
  const float* mask = (const float*)d_in[1];
  const int*   reli = (const int*)d_in[2];
  const float* n1g  = (const float*)d_in[3];
  const float* n1b  = (const float*)d_in[4];
  const float* qkvw = (const float*)d_in[5];
  const float* qkvb = (const float*)d_in[6];
  const float* btab = (const float*)d_in[7];
  const float* pw   = (const float*)d_in[8];
  const float* pb   = (const float*)d_in[9];
  const float* n2g  = (const float*)d_in[10];
  const float* n2b  = (const float*)d_in[11];
  const float* w1   = (const float*)d_in[12];
  const float* b1   = (const float*)d_in[13];
  const float* w2   = (const float*)d_in[14];
  const float* b2   = (const float*)d_in[15];
  float* out = (float*)d_out;

  u16* xn   = (u16*)d_ws;                          // 1024*98*96 bf16
  u16* attn = xn + (size_t)NWIN*98*96;
  u16* Wb   = attn + (size_t)NWIN*98*96;           // qkv 288*96
  u16* Pwb  = Wb + 288*96;                         // 96*96
  u16* W1b  = Pwb + 96*96;                         // 384*96
  u16* W2b  = W1b + 384*96;                        // 96*384
  float* bsc = (float*)(W2b + 96*384);             // 288 f32
  float* comb = bsc + 288;                         // 8*3*112*112 f32

  k0_prep<<<432,   256, 0, stream>>>(qkvw, qkvb, pw, w1, w2, Wb, bsc);
  k0b_comb<<<1176, 256, 0, stream>>>(btab, reli, mask, comb);
  k1_ln  <<<25088, 256, 0, stream>>>(x, n1g, n1b, xn);
  k2_attn<<<3072,  256, 0, stream>>>(xn, Wb, bsc, comb, attn);
  k34_projmlp<<<3136, 256, 0, stream>>>(attn, Pwb, pb, n2g, n2b,
                                        W1b, b1, W2b, b2, x, out);
}

// Round 7
// 178.051 us; speedup vs baseline: 12.3290x; 1.0872x over previous
//
#include <hip/hip_runtime.h>
#include <math.h>

typedef unsigned int u32;
typedef unsigned short u16;

typedef __attribute__((ext_vector_type(8))) short bf16x8;
typedef __attribute__((ext_vector_type(4))) float f32x4;

#define NTOK 98
#define NWIN 1024

// LDS geometry for k2 (u16 units). Total 26640 u16 = 53280 B -> 3 blocks/CU.
#define XS_STR 104
#define QK_STR 40
#define P_STR  136
#define Q_BASE 13328
#define K_BASE 17808
#define VT_BASE 22288
#define LDS_U16 26640

__device__ __forceinline__ float bflo(u32 u){ union{u32 i; float f;} c; c.i = u<<16; return c.f; }
__device__ __forceinline__ float bfhi(u32 u){ union{u32 i; float f;} c; c.i = u & 0xffff0000u; return c.f; }
__device__ __forceinline__ u16 f2bf(float f){
  union{float f; u32 i;} c; c.f = f;
  u32 x = c.i;
  return (u16)((x + 0x7fffu + ((x>>16)&1u)) >> 16);
}

// GELU with A&S 7.1.26 erf (abs err 1.5e-7)
__device__ __forceinline__ float gelu_f(float v){
  float z  = v * 0.70710678118654752f;
  float az = fabsf(z);
  float t  = __builtin_amdgcn_rcpf(1.f + 0.3275911f*az);
  float p  = ((((1.061405429f*t - 1.453152027f)*t + 1.421413741f)*t
               - 0.284496736f)*t + 0.254829592f)*t;
  float er = 1.f - p*__expf(-z*z);
  er = copysignf(er, z);
  return 0.5f*v*(1.f + er);
}

__device__ __forceinline__ int src_token(int win, int t){
  int b  = win >> 9;
  int wr = win & 511;
  int db = wr >> 6, hb = (wr >> 3) & 7, wb = wr & 7;
  int di = t / 49, r = t - di*49;
  int hi = r / 7,  wi = r - hi*7;
  int d = (db*2 + di + 1) & 15;
  int h = hb*7 + hi + 3; if (h >= 56) h -= 56;
  int w = wb*7 + wi + 3; if (w >= 56) w -= 56;
  return ((b*16 + d)*56 + h)*56 + w;
}

// ---------------- K0: preconvert all GEMM weights to bf16 ----------------
__global__ __launch_bounds__(256) void k0_prep(const float* __restrict__ qkvw,
    const float* __restrict__ qkvb, const float* __restrict__ pw,
    const float* __restrict__ w1, const float* __restrict__ w2,
    u16* __restrict__ Wb, float* __restrict__ bs){
  int i = blockIdx.x*256 + threadIdx.x;
  if (i < 288*96){
    float v = qkvw[i];
    if (i < 96*96) v *= 0.17677669529663687f;
    Wb[i] = f2bf(v);
  } else if (i < 288*96 + 96*96){
    Wb[i] = f2bf(pw[i - 288*96]);
  } else if (i < 288*96 + 96*96 + 384*96){
    Wb[i] = f2bf(w1[i - (288*96 + 96*96)]);
  } else if (i < 288*96 + 96*96 + 384*96 + 96*384){
    Wb[i] = f2bf(w2[i - (288*96 + 96*96 + 384*96)]);
  }
  if (i < 288){
    float v = qkvb[i];
    if (i < 96) v *= 0.17677669529663687f;
    bs[i] = v;
  }
}

// ---------------- K0b: comb[m][hd][112][112] = rel_bias + mask ----------------
__global__ __launch_bounds__(256) void k0b_comb(const float* __restrict__ bias_tab,
    const int* __restrict__ rel_idx, const float* __restrict__ mask,
    float* __restrict__ comb){
  int idx = blockIdx.x*256 + threadIdx.x;
  if (idx >= 8*3*112*112) return;
  int m  = idx / 37632; int r1 = idx - m*37632;
  int hd = r1 / 12544;  int r2 = r1 - hd*12544;
  int i  = r2 / 112,    j  = r2 - i*112;
  float v = -1e30f;
  if (i < 98 && j < 98){
    int wr = ((m>>2)&1)*448 + ((m>>1)&1)*56 + (m&1)*7;
    v = bias_tab[rel_idx[i*98+j]*3 + hd] + mask[(size_t)wr*9604 + i*98 + j];
  }
  comb[idx] = v;
}

// ---------------- K1: LN(x2) + shift + window partition -> xn (bf16) ----------------
__global__ __launch_bounds__(256) void k1_ln(const float* __restrict__ x,
      const float* __restrict__ g, const float* __restrict__ bb, u16* __restrict__ xn){
  int wid  = (blockIdx.x << 2) + (threadIdx.x >> 6);
  int lane = threadIdx.x & 63;
  if (wid >= NWIN*NTOK) return;
  int win = wid / NTOK, t = wid - win*NTOK;
  int tok = src_token(win, t);
  const float* xp = x + (size_t)tok*192 + 96;
  float a0 = 0.f, a1 = 0.f;
  if (lane < 48){ float2 v = *(const float2*)(xp + (lane<<1)); a0 = v.x; a1 = v.y; }
  float s = a0 + a1, s2 = a0*a0 + a1*a1;
  #pragma unroll
  for (int o = 32; o; o >>= 1){ s += __shfl_xor(s, o); s2 += __shfl_xor(s2, o); }
  float mean = s * (1.f/96.f);
  float rstd = rsqrtf(s2*(1.f/96.f) - mean*mean + 1e-5f);
  if (lane < 48){
    float r0 = (a0-mean)*rstd*g[2*lane]   + bb[2*lane];
    float r1 = (a1-mean)*rstd*g[2*lane+1] + bb[2*lane+1];
    u32 pk = (u32)f2bf(r0) | ((u32)f2bf(r1) << 16);
    *(u32*)(xn + (size_t)wid*96 + (lane<<1)) = pk;
  }
}

// ---------------- K2: per (window, head) MFMA attention ----------------
__global__ __launch_bounds__(256) void k2_attn(const u16* __restrict__ xn,
    const u16* __restrict__ Wb, const float* __restrict__ bs,
    const float* __restrict__ comb, u16* __restrict__ attn_o){
  __shared__ __align__(16) u16 lds[LDS_U16];
  int tid  = threadIdx.x;
  int lane = tid & 63, wv = tid >> 6;
  int l15  = lane & 15, lg = lane >> 4;
  int win = blockIdx.x / 3, hd = blockIdx.x - win*3;

  {
    const u32* xw = (const u32*)(xn + (size_t)win*98*96);
    u32* xs32 = (u32*)lds;
    for (int i = tid; i < 98*48; i += 256){
      int r = i/48, c = i - r*48;
      xs32[r*52 + c] = xw[i];
    }
    for (int i = tid; i < 14*52; i += 256){
      int r = 98 + i/52, c = i - (i/52)*52;
      xs32[r*52 + c] = 0;
    }
    u32* vt32 = (u32*)(lds + VT_BASE);
    for (int i = tid; i < 32*12; i += 256){
      int d = i/12, c = i - d*12;
      vt32[d*68 + 56 + c] = 0;
    }
  }
  __syncthreads();

  for (int t = wv; t < 42; t += 4){
    f32x4 acc = {0.f,0.f,0.f,0.f};
    if (t < 28){
      int tt = (t < 14) ? t : t - 14;
      int mt = tt >> 1, nt = tt & 1;
      int ch = hd*32 + nt*16 + l15 + ((t < 14) ? 0 : 96);
      const u16* wrow = Wb + ch*96 + lg*8;
      const u16* xsrow = lds + (mt*16 + l15)*XS_STR;
      #pragma unroll
      for (int ks = 0; ks < 3; ks++){
        bf16x8 a = *(const bf16x8*)(xsrow + ks*32 + lg*8);
        bf16x8 b = *(const bf16x8*)(wrow + ks*32);
        acc = __builtin_amdgcn_mfma_f32_16x16x32_bf16(a, b, acc, 0, 0, 0);
      }
      float bias = bs[ch];
      u16* dst = lds + ((t < 14) ? Q_BASE : K_BASE);
      int col = nt*16 + l15;
      int rbase = mt*16 + lg*4;
      #pragma unroll
      for (int r = 0; r < 4; r++)
        dst[(rbase+r)*QK_STR + col] = f2bf(acc[r] + bias);
    } else {
      int tt = t - 28; int mt = tt/7, nt = tt - mt*7;
      int ch = 192 + hd*32 + mt*16 + l15;
      const u16* wrow = Wb + ch*96 + lg*8;
      const u16* xsrow = lds + (nt*16 + l15)*XS_STR;
      #pragma unroll
      for (int ks = 0; ks < 3; ks++){
        bf16x8 a = *(const bf16x8*)(wrow + ks*32);
        bf16x8 b = *(const bf16x8*)(xsrow + ks*32 + lg*8);
        acc = __builtin_amdgcn_mfma_f32_16x16x32_bf16(a, b, acc, 0, 0, 0);
      }
      int dbase = mt*16 + lg*4;
      #pragma unroll
      for (int r = 0; r < 4; r++){
        float bias = bs[192 + hd*32 + dbase + r];
        lds[VT_BASE + (dbase+r)*P_STR + nt*16 + l15] = f2bf(acc[r] + bias);
      }
    }
  }
  __syncthreads();

  {
    int wr = win & 511;
    int maskid = ((wr>>6)==7)*4 + (((wr>>3)&7)==7)*2 + ((wr&7)==7);
    const float* cb_base = comb + (size_t)(maskid*3 + hd)*12544 + l15;

    for (int mt = wv; mt < 7; mt += 4){
      {
        u32* p32 = (u32*)lds;
        int rmax = (mt == 6) ? 2 : 16;
        for (int i = lane; i < rmax*12; i += 64){
          int rr = i/12, c = i - rr*12;
          p32[(mt*16+rr)*68 + 56 + c] = 0;
        }
      }
      int ibase = mt*16 + lg*4;
      float cb[4][7];
      #pragma unroll
      for (int r = 0; r < 4; r++){
        const float* cbp = cb_base + (ibase + r)*112;
        #pragma unroll
        for (int nt = 0; nt < 7; nt++) cb[r][nt] = cbp[nt*16];
      }
      const u16* qrow = lds + Q_BASE + (mt*16 + l15)*QK_STR;
      bf16x8 a = *(const bf16x8*)(qrow + lg*8);
      f32x4 s[7];
      #pragma unroll
      for (int nt = 0; nt < 7; nt++){
        const u16* krow = lds + K_BASE + (nt*16 + l15)*QK_STR;
        bf16x8 b = *(const bf16x8*)(krow + lg*8);
        f32x4 z = {0.f,0.f,0.f,0.f};
        s[nt] = __builtin_amdgcn_mfma_f32_16x16x32_bf16(a, b, z, 0, 0, 0);
      }
      #pragma unroll
      for (int r = 0; r < 4; r++){
        int i = ibase + r;
        float sv[7];
        float mx = -3.0e38f;
        #pragma unroll
        for (int nt = 0; nt < 7; nt++){
          float v = s[nt][r] + cb[r][nt];
          sv[nt] = v; mx = fmaxf(mx, v);
        }
        #pragma unroll
        for (int off = 1; off < 16; off <<= 1) mx = fmaxf(mx, __shfl_xor(mx, off));
        float sum = 0.f;
        #pragma unroll
        for (int nt = 0; nt < 7; nt++){
          float e = __expf(sv[nt] - mx);
          sv[nt] = e; sum += e;
        }
        #pragma unroll
        for (int off = 1; off < 16; off <<= 1) sum += __shfl_xor(sum, off);
        float inv = 1.f / sum;
        if (i < 98){
          #pragma unroll
          for (int nt = 0; nt < 7; nt++)
            lds[i*P_STR + nt*16 + l15] = f2bf(sv[nt]*inv);
        }
      }
    }
  }
  __syncthreads();

  for (int t = wv; t < 14; t += 4){
    int mt = t >> 1, nt = t & 1;
    const u16* prow = lds + (mt*16 + l15)*P_STR;
    const u16* vrow = lds + VT_BASE + (nt*16 + l15)*P_STR;
    f32x4 acc = {0.f,0.f,0.f,0.f};
    #pragma unroll
    for (int ks = 0; ks < 4; ks++){
      bf16x8 a = *(const bf16x8*)(prow + ks*32 + lg*8);
      bf16x8 b = *(const bf16x8*)(vrow + ks*32 + lg*8);
      acc = __builtin_amdgcn_mfma_f32_16x16x32_bf16(a, b, acc, 0, 0, 0);
    }
    int ibase = mt*16 + lg*4;
    int d = nt*16 + l15;
    #pragma unroll
    for (int r = 0; r < 4; r++){
      int i = ibase + r;
      if (i < 98) attn_o[((size_t)win*98 + i)*96 + hd*32 + d] = f2bf(acc[r]);
    }
  }
}

// ---------------- K34: fused proj + x1 + LN + fc1 + GELU + fc2 + x2 ----------------
// 32 windowed tokens/block. LDS u16 layout:
//   H [0, 12544)  (fc1 out, 32x392)   overlays: aw [0,3328) (32x104), y1f f32 @ [3328,9728)
//   yn [12544, 15872)  (32x104 bf16)
//   tok_s @ [15872, 15936)  (32 int)
// Total 31872 B.
#define HS 392
#define Y1F_U16 3328
#define YN_U16 12544
#define TOK_U16 15872
__global__ __launch_bounds__(256, 4) void k34_projmlp(const u16* __restrict__ attn_o,
    const u16* __restrict__ Pwb, const float* __restrict__ pb,
    const float* __restrict__ g2, const float* __restrict__ b2,
    const u16* __restrict__ W1b, const float* __restrict__ b1,
    const u16* __restrict__ W2b, const float* __restrict__ bb2,
    const float* __restrict__ x, float* __restrict__ out){
  __shared__ __align__(16) u16 lds[15936];
  int tid = threadIdx.x;
  int lane = tid & 63, wv = tid >> 6;
  int l15 = lane & 15, lg = lane >> 4;
  size_t base = (size_t)blockIdx.x * 32;
  float* y1f = (float*)(lds + Y1F_U16);
  int* tok_s = (int*)(lds + TOK_U16);

  // ---- stage aw (32x96 bf16, stride 104) + token map ----
  {
    const u32* src = (const u32*)(attn_o + base*96);
    u32* aw32 = (u32*)lds;
    #pragma unroll
    for (int k = 0; k < 6; k++){
      int i = tid + k*256;
      int r = i/48, c = i - r*48;
      aw32[r*52 + c] = src[i];
    }
    if (tid < 32){
      int wt = (int)base + tid; int win = wt/98;
      tok_s[tid] = src_token(win, wt - win*98);
    }
  }
  __syncthreads();

  // ---- proj + x1 residual -> out[...,0:96] and y1f. Dual m-tile chains. ----
  {
    const u16* a0p = lds + l15*104 + lg*8;
    const u16* a1p = a0p + 16*104;
    bf16x8 a00=*(const bf16x8*)(a0p), a01=*(const bf16x8*)(a0p+32), a02=*(const bf16x8*)(a0p+64);
    bf16x8 a10=*(const bf16x8*)(a1p), a11=*(const bf16x8*)(a1p+32), a12=*(const bf16x8*)(a1p+64);
    for (int nt = wv; nt < 6; nt += 4){
      const u16* wrow = Pwb + (nt*16 + l15)*96 + lg*8;
      bf16x8 w0=*(const bf16x8*)(wrow), w1=*(const bf16x8*)(wrow+32), w2=*(const bf16x8*)(wrow+64);
      f32x4 acc0 = {0.f,0.f,0.f,0.f}, acc1 = {0.f,0.f,0.f,0.f};
      acc0 = __builtin_amdgcn_mfma_f32_16x16x32_bf16(a00, w0, acc0, 0, 0, 0);
      acc1 = __builtin_amdgcn_mfma_f32_16x16x32_bf16(a10, w0, acc1, 0, 0, 0);
      acc0 = __builtin_amdgcn_mfma_f32_16x16x32_bf16(a01, w1, acc0, 0, 0, 0);
      acc1 = __builtin_amdgcn_mfma_f32_16x16x32_bf16(a11, w1, acc1, 0, 0, 0);
      acc0 = __builtin_amdgcn_mfma_f32_16x16x32_bf16(a02, w2, acc0, 0, 0, 0);
      acc1 = __builtin_amdgcn_mfma_f32_16x16x32_bf16(a12, w2, acc1, 0, 0, 0);
      int n = nt*16 + l15;
      float bias = pb[n];
      #pragma unroll
      for (int r = 0; r < 4; r++){
        int row = lg*4 + r; int tok = tok_s[row];
        float y = acc0[r] + bias + x[(size_t)tok*192 + n];
        out[(size_t)tok*192 + n] = y;
        y1f[row*100 + n] = y;
      }
      #pragma unroll
      for (int r = 0; r < 4; r++){
        int row = 16 + lg*4 + r; int tok = tok_s[row];
        float y = acc1[r] + bias + x[(size_t)tok*192 + n];
        out[(size_t)tok*192 + n] = y;
        y1f[row*100 + n] = y;
      }
    }
  }
  __syncthreads();

  // ---- LN(y1) -> yn (bf16). 8 threads/token. ----
  {
    int tk = tid >> 3, c8 = tid & 7;
    const float4* yp = (const float4*)(y1f + tk*100 + c8*12);
    float4 v4[3];
    #pragma unroll
    for (int j = 0; j < 3; j++) v4[j] = yp[j];
    float s = 0.f, s2 = 0.f;
    #pragma unroll
    for (int j = 0; j < 3; j++){
      s  += v4[j].x + v4[j].y + v4[j].z + v4[j].w;
      s2 += v4[j].x*v4[j].x + v4[j].y*v4[j].y + v4[j].z*v4[j].z + v4[j].w*v4[j].w;
    }
    s  += __shfl_xor(s, 1);  s  += __shfl_xor(s, 2);  s  += __shfl_xor(s, 4);
    s2 += __shfl_xor(s2, 1); s2 += __shfl_xor(s2, 2); s2 += __shfl_xor(s2, 4);
    float mean = s * (1.f/96.f);
    float rstd = rsqrtf(s2*(1.f/96.f) - mean*mean + 1e-5f);
    u32* dst = (u32*)(lds + YN_U16) + tk*52 + c8*6;
    const float* gp = g2 + c8*12;
    const float* bp = b2 + c8*12;
    #pragma unroll
    for (int p = 0; p < 6; p++){
      float e0 = (p & 1) ? v4[p>>1].z : v4[p>>1].x;
      float e1 = (p & 1) ? v4[p>>1].w : v4[p>>1].y;
      float r0 = (e0 - mean)*rstd*gp[2*p]   + bp[2*p];
      float r1 = (e1 - mean)*rstd*gp[2*p+1] + bp[2*p+1];
      dst[p] = (u32)f2bf(r0) | ((u32)f2bf(r1) << 16);
    }
  }
  __syncthreads();

  // ---- fc1 + GELU -> H. Wave owns 6 n-tiles x BOTH m-tiles (dual chains,
  //      shared weights, 1-deep prefetch). ----
  {
    const u16* a0p = lds + YN_U16 + l15*104 + lg*8;
    const u16* a1p = a0p + 16*104;
    bf16x8 a00=*(const bf16x8*)(a0p), a01=*(const bf16x8*)(a0p+32), a02=*(const bf16x8*)(a0p+64);
    bf16x8 a10=*(const bf16x8*)(a1p), a11=*(const bf16x8*)(a1p+32), a12=*(const bf16x8*)(a1p+64);
    const u16* wp = W1b + ((wv*6)*16 + l15)*96 + lg*8;
    bf16x8 w0=*(const bf16x8*)(wp), w1=*(const bf16x8*)(wp+32), w2=*(const bf16x8*)(wp+64);
    #pragma unroll
    for (int q = 0; q < 6; q++){
      bf16x8 c0=w0, c1=w1, c2=w2;
      if (q < 5){
        const u16* nw = wp + (q+1)*1536;
        w0=*(const bf16x8*)(nw); w1=*(const bf16x8*)(nw+32); w2=*(const bf16x8*)(nw+64);
      }
      f32x4 acc0 = {0.f,0.f,0.f,0.f}, acc1 = {0.f,0.f,0.f,0.f};
      acc0 = __builtin_amdgcn_mfma_f32_16x16x32_bf16(a00, c0, acc0, 0, 0, 0);
      acc1 = __builtin_amdgcn_mfma_f32_16x16x32_bf16(a10, c0, acc1, 0, 0, 0);
      acc0 = __builtin_amdgcn_mfma_f32_16x16x32_bf16(a01, c1, acc0, 0, 0, 0);
      acc1 = __builtin_amdgcn_mfma_f32_16x16x32_bf16(a11, c1, acc1, 0, 0, 0);
      acc0 = __builtin_amdgcn_mfma_f32_16x16x32_bf16(a02, c2, acc0, 0, 0, 0);
      acc1 = __builtin_amdgcn_mfma_f32_16x16x32_bf16(a12, c2, acc1, 0, 0, 0);
      int n = (wv*6 + q)*16 + l15;
      float bias = b1[n];
      #pragma unroll
      for (int r = 0; r < 4; r++)
        lds[(lg*4 + r)*HS + n] = f2bf(gelu_f(acc0[r] + bias));
      #pragma unroll
      for (int r = 0; r < 4; r++)
        lds[(16 + lg*4 + r)*HS + n] = f2bf(gelu_f(acc1[r] + bias));
    }
  }
  __syncthreads();

  // ---- fc2 + bias + x2 residual. Two independent K-half chains. ----
  {
    int mt = wv & 1, ng = wv >> 1;
    const u16* arow = lds + (mt*16 + l15)*HS + lg*8;
    bf16x8 ar[12];
    #pragma unroll
    for (int ks = 0; ks < 12; ks++) ar[ks] = *(const bf16x8*)(arow + ks*32);
    #pragma unroll
    for (int q = 0; q < 3; q++){
      int ct = ng*3 + q;
      const u16* wrow = W2b + (ct*16 + l15)*384 + lg*8;
      f32x4 aA = {0.f,0.f,0.f,0.f}, aB = {0.f,0.f,0.f,0.f};
      #pragma unroll
      for (int ks = 0; ks < 6; ks++){
        bf16x8 wa = *(const bf16x8*)(wrow + ks*32);
        bf16x8 wb = *(const bf16x8*)(wrow + (ks+6)*32);
        aA = __builtin_amdgcn_mfma_f32_16x16x32_bf16(ar[ks],   wa, aA, 0, 0, 0);
        aB = __builtin_amdgcn_mfma_f32_16x16x32_bf16(ar[ks+6], wb, aB, 0, 0, 0);
      }
      int c = ct*16 + l15;
      float bias = bb2[c];
      #pragma unroll
      for (int r = 0; r < 4; r++){
        int row = mt*16 + lg*4 + r;
        size_t o = (size_t)tok_s[row]*192 + 96 + c;
        out[o] = x[o] + aA[r] + aB[r] + bias;
      }
    }
  }
}

extern "C" void kernel_launch(void* const* d_in, const int* in_sizes, int n_in,
                              void* d_out, int out_size, void* d_ws, size_t ws_size,
                              hipStream_t stream){
  const float* x    = (const float*)d_in[0];
  const float* mask = (const float*)d_in[1];
  const int*   reli = (const int*)d_in[2];
  const float* n1g  = (const float*)d_in[3];
  const float* n1b  = (const float*)d_in[4];
  const float* qkvw = (const float*)d_in[5];
  const float* qkvb = (const float*)d_in[6];
  const float* btab = (const float*)d_in[7];
  const float* pw   = (const float*)d_in[8];
  const float* pb   = (const float*)d_in[9];
  const float* n2g  = (const float*)d_in[10];
  const float* n2b  = (const float*)d_in[11];
  const float* w1   = (const float*)d_in[12];
  const float* b1   = (const float*)d_in[13];
  const float* w2   = (const float*)d_in[14];
  const float* b2   = (const float*)d_in[15];
  float* out = (float*)d_out;

  u16* xn   = (u16*)d_ws;                          // 1024*98*96 bf16
  u16* attn = xn + (size_t)NWIN*98*96;
  u16* Wb   = attn + (size_t)NWIN*98*96;           // qkv 288*96
  u16* Pwb  = Wb + 288*96;                         // 96*96
  u16* W1b  = Pwb + 96*96;                         // 384*96
  u16* W2b  = W1b + 384*96;                        // 96*384
  float* bsc = (float*)(W2b + 96*384);             // 288 f32
  float* comb = bsc + 288;                         // 8*3*112*112 f32

  k0_prep<<<432,   256, 0, stream>>>(qkvw, qkvb, pw, w1, w2, Wb, bsc);
  k0b_comb<<<1176, 256, 0, stream>>>(btab, reli, mask, comb);
  k1_ln  <<<25088, 256, 0, stream>>>(x, n1g, n1b, xn);
  k2_attn<<<3072,  256, 0, stream>>>(xn, Wb, bsc, comb, attn);
  k34_projmlp<<<3136, 256, 0, stream>>>(attn, Pwb, pb, n2g, n2b,
                                        W1b, b1, W2b, b2, x, out);
}